// Round 1
// baseline (338.824 us; speedup 1.0000x reference)
//
#include <hip/hip_runtime.h>
#include <hip/hip_bf16.h>
#include <stdint.h>

// Problem constants
#define S_LEN 2048
#define BATCH 2
#define EMB   1024
#define NH    16
#define DHEAD 64
#define ROWS  (S_LEN*BATCH)   // 4096
#define SCALE_Q 0.125f        // DH^-0.5

typedef __attribute__((ext_vector_type(8))) short bf16x8;   // 8 bf16 in 4 VGPRs
typedef __attribute__((ext_vector_type(4))) float f32x4;

typedef const __attribute__((address_space(1))) void* gas_ptr;
typedef __attribute__((address_space(3))) void* las_ptr;
// async global->LDS, 16B per lane, dest = wave-uniform base + lane*16
#define GLD16(g, l) __builtin_amdgcn_global_load_lds((gas_ptr)(g), (las_ptr)(l), 16, 0, 0)

__device__ __forceinline__ unsigned short f2b(float f) {
  union { float f; unsigned int u; } v; v.f = f;
  unsigned int u = v.u;
  unsigned int r = (u + 0x7FFFu + ((u >> 16) & 1u)) >> 16;  // RNE
  return (unsigned short)r;
}

// ---------------- fp32 -> bf16 conversion ----------------
__device__ __forceinline__ void cvt8(const float* __restrict__ s,
                                     unsigned short* __restrict__ d, size_t i) {
  float4 a = *reinterpret_cast<const float4*>(s + i);
  float4 b = *reinterpret_cast<const float4*>(s + i + 4);
  uint4 o;
  o.x = (unsigned)f2b(a.x) | ((unsigned)f2b(a.y) << 16);
  o.y = (unsigned)f2b(a.z) | ((unsigned)f2b(a.w) << 16);
  o.z = (unsigned)f2b(b.x) | ((unsigned)f2b(b.y) << 16);
  o.w = (unsigned)f2b(b.z) | ((unsigned)f2b(b.w) << 16);
  *reinterpret_cast<uint4*>(d + i) = o;
}

__global__ __launch_bounds__(256) void cvt_kernel(const float* __restrict__ s,
                                                  unsigned short* __restrict__ d) {
  size_t i = ((size_t)blockIdx.x * 256 + threadIdx.x) * 8;
  cvt8(s, d, i);
}

__global__ __launch_bounds__(256) void cvt4_kernel(
    const float* __restrict__ s0, const float* __restrict__ s1,
    const float* __restrict__ s2, const float* __restrict__ s3,
    unsigned short* __restrict__ d0, unsigned short* __restrict__ d1,
    unsigned short* __restrict__ d2, unsigned short* __restrict__ d3) {
  const float* s; unsigned short* d;
  switch (blockIdx.y) {
    case 0:  s = s0; d = d0; break;
    case 1:  s = s1; d = d1; break;
    case 2:  s = s2; d = d2; break;
    default: s = s3; d = d3; break;
  }
  size_t i = ((size_t)blockIdx.x * 256 + threadIdx.x) * 8;
  cvt8(s, d, i);
}

// ---------------- shared GEMM mainloop (C = A * B^T), 128x128 tile, BK=32 ----------------
// A: [M x 1024] bf16 row-major. Bw: [N x 1024] bf16 row-major (i.e. B^T layout).
// 4 waves (2x2), each wave 64x64 = 4x4 fragments of 16x16, K-step 32 (one MFMA K).
__device__ __forceinline__ void gemm_mainloop(const unsigned short* __restrict__ A,
                                              const unsigned short* __restrict__ Bw,
                                              int m0, int n0, f32x4 acc[4][4]) {
  __shared__ unsigned short Abuf[128 * 32];
  __shared__ unsigned short Bbuf[128 * 32];
  const int t    = threadIdx.x;
  const int lane = t & 63;
  const int w    = t >> 6;
  const int wr   = w >> 1, wc = w & 1;
  const int lm   = lane & 15;
  const int lkb  = (lane >> 4) * 8;       // k offset within 32 (elements)

  f32x4 zf = {0.0f, 0.0f, 0.0f, 0.0f};
#pragma unroll
  for (int i = 0; i < 4; ++i)
#pragma unroll
    for (int j = 0; j < 4; ++j) acc[i][j] = zf;

  for (int k0 = 0; k0 < EMB; k0 += 32) {
    // stage A,B tiles: 512 chunks of 16B each; thread t -> chunks t, t+256
#pragma unroll
    for (int q = 0; q < 2; ++q) {
      int c = t + q * 256;
      int r = c >> 2, ci = c & 3;           // row, 16B-chunk in row (32 bf16 = 4 chunks)
      GLD16(A  + (size_t)(m0 + r) * EMB + k0 + ci * 8,
            (char*)Abuf + (size_t)(q * 256 + w * 64) * 16);
      GLD16(Bw + (size_t)(n0 + r) * EMB + k0 + ci * 8,
            (char*)Bbuf + (size_t)(q * 256 + w * 64) * 16);
    }
    __syncthreads();

    bf16x8 af[4], bfr[4];
#pragma unroll
    for (int i = 0; i < 4; ++i)
      af[i] = *reinterpret_cast<const bf16x8*>(&Abuf[(wr * 64 + i * 16 + lm) * 32 + lkb]);
#pragma unroll
    for (int j = 0; j < 4; ++j)
      bfr[j] = *reinterpret_cast<const bf16x8*>(&Bbuf[(wc * 64 + j * 16 + lm) * 32 + lkb]);
#pragma unroll
    for (int i = 0; i < 4; ++i)
#pragma unroll
      for (int j = 0; j < 4; ++j)
        acc[i][j] = __builtin_amdgcn_mfma_f32_16x16x32_bf16(af[i], bfr[j], acc[i][j], 0, 0, 0);
    __syncthreads();
  }
}

// ---------------- QKV projection: out = (X @ W^T + b) [*scale], scatter to [B,H,S,DH] bf16 ----
__global__ __launch_bounds__(256) void gemm_qkv_kernel(
    const unsigned short* __restrict__ X,
    const unsigned short* __restrict__ Wq, const unsigned short* __restrict__ Wk,
    const unsigned short* __restrict__ Wv,
    const float* __restrict__ bq, const float* __restrict__ bk, const float* __restrict__ bv,
    unsigned short* __restrict__ Qb, unsigned short* __restrict__ Kb,
    unsigned short* __restrict__ Vb) {
  const int m0 = blockIdx.x * 128;
  const int n0 = blockIdx.y * 128;
  const int z  = blockIdx.z;
  const unsigned short* Bw = (z == 0) ? Wq : (z == 1) ? Wk : Wv;
  const float* bias        = (z == 0) ? bq : (z == 1) ? bk : bv;
  unsigned short* Out      = (z == 0) ? Qb : (z == 1) ? Kb : Vb;
  const float scale        = (z == 0) ? SCALE_Q : 1.0f;

  f32x4 acc[4][4];
  gemm_mainloop(X, Bw, m0, n0, acc);

  const int lane = threadIdx.x & 63;
  const int w    = threadIdx.x >> 6;
  const int wr   = w >> 1, wc = w & 1;
  const int lm   = lane & 15, lq = lane >> 4;
#pragma unroll
  for (int j = 0; j < 4; ++j) {
    int col = n0 + wc * 64 + j * 16 + lm;      // E index
    int h = col >> 6, dd = col & 63;
    float bc = bias[col];
#pragma unroll
    for (int i = 0; i < 4; ++i) {
#pragma unroll
      for (int r = 0; r < 4; ++r) {
        int row = m0 + wr * 64 + i * 16 + lq * 4 + r;   // s*B + b
        int s = row >> 1, b = row & 1;
        float v = (acc[i][j][r] + bc) * scale;
        Out[((size_t)(b * NH + h) * S_LEN + s) * DHEAD + dd] = f2b(v);
      }
    }
  }
}

// ---------------- final projection: out = Ctx @ Wo^T + bo (fp32 out) ----------------
__global__ __launch_bounds__(256) void gemm_out_kernel(
    const unsigned short* __restrict__ Ctx, const unsigned short* __restrict__ Wo,
    const float* __restrict__ bo, float* __restrict__ Out) {
  const int m0 = blockIdx.x * 128;
  const int n0 = blockIdx.y * 128;
  f32x4 acc[4][4];
  gemm_mainloop(Ctx, Wo, m0, n0, acc);

  const int lane = threadIdx.x & 63;
  const int w    = threadIdx.x >> 6;
  const int wr   = w >> 1, wc = w & 1;
  const int lm   = lane & 15, lq = lane >> 4;
#pragma unroll
  for (int j = 0; j < 4; ++j) {
    int col = n0 + wc * 64 + j * 16 + lm;
    float bc = bo[col];
#pragma unroll
    for (int i = 0; i < 4; ++i) {
#pragma unroll
      for (int r = 0; r < 4; ++r) {
        int row = m0 + wr * 64 + i * 16 + lq * 4 + r;
        Out[(size_t)row * EMB + col] = acc[i][j][r] + bc;
      }
    }
  }
}

// ---------------- flash attention ----------------
// grid: (B*H, S/128). 4 waves/block, each wave owns 32 q-rows (2 M-frags).
// K-tile 32 kv x 64 d staged via global_load_lds with XOR source-swizzle
// (row-major [32][128B] is a 16-way bank-conflict without it).
// V staged transposed (Vt[d][kv]) so the PV B-fragment is a contiguous b128 read.
__global__ __launch_bounds__(256) void attn_kernel(
    const unsigned short* __restrict__ Qb, const unsigned short* __restrict__ Kb,
    const unsigned short* __restrict__ Vb, unsigned short* __restrict__ Ctx) {
  const int bh = blockIdx.x;            // b*NH + h
  const int q0 = blockIdx.y * 128;
  const int t    = threadIdx.x;
  const int lane = t & 63;
  const int w    = t >> 6;
  const int lm   = lane & 15, lq = lane >> 4;
  const size_t base = (size_t)bh * S_LEN * DHEAD;
  const unsigned short* Q = Qb + base;
  const unsigned short* K = Kb + base;
  const unsigned short* V = Vb + base;

  __shared__ unsigned short Klds[32 * 64];       // swizzled row-major [32][64]
  __shared__ unsigned short Vt[64 * 32];         // [d][kv]
  __shared__ unsigned short Plds[4][32 * 32];    // per-wave P tile

  const int qw = q0 + w * 32;

  // Q fragments held in registers for the whole kernel (A-operand layout)
  bf16x8 aq[2][2];
#pragma unroll
  for (int mi = 0; mi < 2; ++mi)
#pragma unroll
    for (int kk = 0; kk < 2; ++kk)
      aq[mi][kk] = *reinterpret_cast<const bf16x8*>(
          Q + (size_t)(qw + mi * 16 + lm) * DHEAD + kk * 32 + lq * 8);

  f32x4 accO[2][4];
  float m_st[2][4], l_st[2][4];
  f32x4 zf = {0.0f, 0.0f, 0.0f, 0.0f};
#pragma unroll
  for (int mi = 0; mi < 2; ++mi) {
#pragma unroll
    for (int ni = 0; ni < 4; ++ni) accO[mi][ni] = zf;
#pragma unroll
    for (int r = 0; r < 4; ++r) { m_st[mi][r] = -1e30f; l_st[mi][r] = 0.0f; }
  }

  for (int kb = 0; kb < S_LEN; kb += 32) {
    // stage K tile: 256 16B chunks, one per thread; inverse-swizzled source,
    // linear LDS dest (chunk t -> row t>>3, slot t&7 stores logical chunk (t&7)^(row&7))
    {
      int r = t >> 3, p = t & 7;
      int lc = p ^ (r & 7);
      GLD16(K + (size_t)(kb + r) * DHEAD + lc * 8, (char*)Klds + (size_t)(w * 64) * 16);
    }
    // stage V transposed: thread reads 8 contiguous d of one kv row, scatters to Vt
    {
      int j = t >> 3, d0 = (t & 7) * 8;
      bf16x8 v8 = *reinterpret_cast<const bf16x8*>(V + (size_t)(kb + j) * DHEAD + d0);
#pragma unroll
      for (int e = 0; e < 8; ++e) Vt[(d0 + e) * 32 + j] = (unsigned short)v8[e];
    }
    __syncthreads();

    // S = Q K^T  (A = Q rows, B = K^T: lane reads 8 contiguous d of K row ji*16+lm)
    bf16x8 bkf[2][2];   // [kk][ji]
#pragma unroll
    for (int kk = 0; kk < 2; ++kk)
#pragma unroll
      for (int ji = 0; ji < 2; ++ji) {
        int r = ji * 16 + lm;
        int dc = kk * 4 + lq;                 // logical 16B chunk within row
        int slot = dc ^ (r & 7);              // swizzled slot
        bkf[kk][ji] = *reinterpret_cast<const bf16x8*>(&Klds[r * 64 + slot * 8]);
      }
    f32x4 sfr[2][2];
#pragma unroll
    for (int mi = 0; mi < 2; ++mi)
#pragma unroll
      for (int ji = 0; ji < 2; ++ji) {
        f32x4 s = __builtin_amdgcn_mfma_f32_16x16x32_bf16(aq[mi][0], bkf[0][ji], zf, 0, 0, 0);
        sfr[mi][ji] = __builtin_amdgcn_mfma_f32_16x16x32_bf16(aq[mi][1], bkf[1][ji], s, 0, 0, 0);
      }

    // online softmax (rows live at (lq*4+r); cols are the 16 lanes of each quarter)
#pragma unroll
    for (int mi = 0; mi < 2; ++mi) {
#pragma unroll
      for (int r = 0; r < 4; ++r) {
        float tm = fmaxf(sfr[mi][0][r], sfr[mi][1][r]);
        tm = fmaxf(tm, __shfl_xor(tm, 1, 16));
        tm = fmaxf(tm, __shfl_xor(tm, 2, 16));
        tm = fmaxf(tm, __shfl_xor(tm, 4, 16));
        tm = fmaxf(tm, __shfl_xor(tm, 8, 16));
        float mo = m_st[mi][r];
        float mn = fmaxf(mo, tm);
        float sc = __expf(mo - mn);
        float p0 = __expf(sfr[mi][0][r] - mn);
        float p1 = __expf(sfr[mi][1][r] - mn);
        sfr[mi][0][r] = p0; sfr[mi][1][r] = p1;
        float ps = p0 + p1;
        ps += __shfl_xor(ps, 1, 16);
        ps += __shfl_xor(ps, 2, 16);
        ps += __shfl_xor(ps, 4, 16);
        ps += __shfl_xor(ps, 8, 16);
        l_st[mi][r] = l_st[mi][r] * sc + ps;
        m_st[mi][r] = mn;
#pragma unroll
        for (int ni = 0; ni < 4; ++ni) accO[mi][ni][r] *= sc;
      }
    }

    // P (C-layout) -> per-wave LDS as bf16
    unsigned short* Pw = Plds[w];
#pragma unroll
    for (int mi = 0; mi < 2; ++mi)
#pragma unroll
      for (int ji = 0; ji < 2; ++ji)
#pragma unroll
        for (int r = 0; r < 4; ++r)
          Pw[(mi * 16 + lq * 4 + r) * 32 + ji * 16 + lm] = f2b(sfr[mi][ji][r]);

    // O += P V  (A = P from LDS in A-layout, B = Vt contiguous kv)
    bf16x8 bv4[4];
#pragma unroll
    for (int ni = 0; ni < 4; ++ni)
      bv4[ni] = *reinterpret_cast<const bf16x8*>(&Vt[(ni * 16 + lm) * 32 + lq * 8]);
#pragma unroll
    for (int mi = 0; mi < 2; ++mi) {
      bf16x8 ap = *reinterpret_cast<const bf16x8*>(&Pw[(mi * 16 + lm) * 32 + lq * 8]);
#pragma unroll
      for (int ni = 0; ni < 4; ++ni)
        accO[mi][ni] = __builtin_amdgcn_mfma_f32_16x16x32_bf16(ap, bv4[ni], accO[mi][ni], 0, 0, 0);
    }
    __syncthreads();
  }

  // epilogue: normalize rows, write ctx as [S,B,E] bf16
  const int b = bh >> 4, h = bh & 15;
#pragma unroll
  for (int mi = 0; mi < 2; ++mi) {
#pragma unroll
    for (int r = 0; r < 4; ++r) {
      float rl = 1.0f / l_st[mi][r];
      int srow = qw + mi * 16 + lq * 4 + r;
      size_t rowbase = ((size_t)srow * BATCH + b) * EMB + (size_t)h * 64;
#pragma unroll
      for (int ni = 0; ni < 4; ++ni)
        Ctx[rowbase + ni * 16 + lm] = f2b(accO[mi][ni][r] * rl);
    }
  }
}

// ---------------- launch ----------------
extern "C" void kernel_launch(void* const* d_in, const int* in_sizes, int n_in,
                              void* d_out, int out_size, void* d_ws, size_t ws_size,
                              hipStream_t stream) {
  const float* query = (const float*)d_in[0];
  const float* wq = (const float*)d_in[1];
  const float* bq = (const float*)d_in[2];
  const float* wk = (const float*)d_in[3];
  const float* bk = (const float*)d_in[4];
  const float* wv = (const float*)d_in[5];
  const float* bv = (const float*)d_in[6];
  const float* wo = (const float*)d_in[7];
  const float* bo = (const float*)d_in[8];
  float* out = (float*)d_out;

  unsigned short* p = (unsigned short*)d_ws;
  unsigned short* Xbf = p;                        p += (size_t)ROWS * EMB;   // 8 MB
  unsigned short* Wqb = p;                        p += (size_t)EMB * EMB;
  unsigned short* Wkb = p;                        p += (size_t)EMB * EMB;
  unsigned short* Wvb = p;                        p += (size_t)EMB * EMB;
  unsigned short* Wob = p;                        p += (size_t)EMB * EMB;
  unsigned short* Qb  = p;                        p += (size_t)ROWS * EMB;   // [B,H,S,DH]
  unsigned short* Kb  = p;                        p += (size_t)ROWS * EMB;
  unsigned short* Vb  = p;                        p += (size_t)ROWS * EMB;
  unsigned short* Ctx = p;                        p += (size_t)ROWS * EMB;

  cvt_kernel<<<ROWS * EMB / 8 / 256, 256, 0, stream>>>(query, Xbf);
  cvt4_kernel<<<dim3(EMB * EMB / 8 / 256, 4), 256, 0, stream>>>(
      wq, wk, wv, wo, Wqb, Wkb, Wvb, Wob);
  gemm_qkv_kernel<<<dim3(ROWS / 128, EMB / 128, 3), 256, 0, stream>>>(
      Xbf, Wqb, Wkb, Wvb, bq, bk, bv, Qb, Kb, Vb);
  attn_kernel<<<dim3(BATCH * NH, S_LEN / 128), 256, 0, stream>>>(Qb, Kb, Vb, Ctx);
  gemm_out_kernel<<<dim3(ROWS / 128, EMB / 128), 256, 0, stream>>>(Ctx, Wob, bo, out);
}

// Round 2
// 228.164 us; speedup vs baseline: 1.4850x; 1.4850x over previous
//
#include <hip/hip_runtime.h>
#include <hip/hip_bf16.h>
#include <stdint.h>

// Problem constants
#define S_LEN 2048
#define BATCH 2
#define EMB   1024
#define NH    16
#define DHEAD 64
#define ROWS  (S_LEN*BATCH)   // 4096
#define SCALE_Q 0.125f        // DH^-0.5

typedef __attribute__((ext_vector_type(8))) short bf16x8;   // 8 bf16 in 4 VGPRs
typedef __attribute__((ext_vector_type(4))) float f32x4;

typedef const __attribute__((address_space(1))) void* gas_ptr;
typedef __attribute__((address_space(3))) void* las_ptr;
// async global->LDS, 16B per lane, dest = wave-uniform base + lane*16
#define GLD16(g, l) __builtin_amdgcn_global_load_lds((gas_ptr)(g), (las_ptr)(l), 16, 0, 0)

__device__ __forceinline__ unsigned short f2b(float f) {
  union { float f; unsigned int u; } v; v.f = f;
  unsigned int u = v.u;
  unsigned int r = (u + 0x7FFFu + ((u >> 16) & 1u)) >> 16;  // RNE
  return (unsigned short)r;
}

// ---------------- fp32 -> bf16 conversion ----------------
__device__ __forceinline__ void cvt8(const float* __restrict__ s,
                                     unsigned short* __restrict__ d, size_t i) {
  float4 a = *reinterpret_cast<const float4*>(s + i);
  float4 b = *reinterpret_cast<const float4*>(s + i + 4);
  uint4 o;
  o.x = (unsigned)f2b(a.x) | ((unsigned)f2b(a.y) << 16);
  o.y = (unsigned)f2b(a.z) | ((unsigned)f2b(a.w) << 16);
  o.z = (unsigned)f2b(b.x) | ((unsigned)f2b(b.y) << 16);
  o.w = (unsigned)f2b(b.z) | ((unsigned)f2b(b.w) << 16);
  *reinterpret_cast<uint4*>(d + i) = o;
}

__global__ __launch_bounds__(256) void cvt_kernel(const float* __restrict__ s,
                                                  unsigned short* __restrict__ d) {
  size_t i = ((size_t)blockIdx.x * 256 + threadIdx.x) * 8;
  cvt8(s, d, i);
}

__global__ __launch_bounds__(256) void cvt4_kernel(
    const float* __restrict__ s0, const float* __restrict__ s1,
    const float* __restrict__ s2, const float* __restrict__ s3,
    unsigned short* __restrict__ d0, unsigned short* __restrict__ d1,
    unsigned short* __restrict__ d2, unsigned short* __restrict__ d3) {
  const float* s; unsigned short* d;
  switch (blockIdx.y) {
    case 0:  s = s0; d = d0; break;
    case 1:  s = s1; d = d1; break;
    case 2:  s = s2; d = d2; break;
    default: s = s3; d = d3; break;
  }
  size_t i = ((size_t)blockIdx.x * 256 + threadIdx.x) * 8;
  cvt8(s, d, i);
}

// ---------------- shared GEMM mainloop (C = A * B^T), 128x128 tile, BK=32 ----------------
__device__ __forceinline__ void gemm_mainloop(const unsigned short* __restrict__ A,
                                              const unsigned short* __restrict__ Bw,
                                              int m0, int n0, f32x4 acc[4][4]) {
  __shared__ unsigned short Abuf[128 * 32];
  __shared__ unsigned short Bbuf[128 * 32];
  const int t    = threadIdx.x;
  const int lane = t & 63;
  const int w    = t >> 6;
  const int wr   = w >> 1, wc = w & 1;
  const int lm   = lane & 15;
  const int lkb  = (lane >> 4) * 8;       // k offset within 32 (elements)

  f32x4 zf = {0.0f, 0.0f, 0.0f, 0.0f};
#pragma unroll
  for (int i = 0; i < 4; ++i)
#pragma unroll
    for (int j = 0; j < 4; ++j) acc[i][j] = zf;

  for (int k0 = 0; k0 < EMB; k0 += 32) {
#pragma unroll
    for (int q = 0; q < 2; ++q) {
      int c = t + q * 256;
      int r = c >> 2, ci = c & 3;
      GLD16(A  + (size_t)(m0 + r) * EMB + k0 + ci * 8,
            (char*)Abuf + (size_t)(q * 256 + w * 64) * 16);
      GLD16(Bw + (size_t)(n0 + r) * EMB + k0 + ci * 8,
            (char*)Bbuf + (size_t)(q * 256 + w * 64) * 16);
    }
    __syncthreads();

    bf16x8 af[4], bfr[4];
#pragma unroll
    for (int i = 0; i < 4; ++i)
      af[i] = *reinterpret_cast<const bf16x8*>(&Abuf[(wr * 64 + i * 16 + lm) * 32 + lkb]);
#pragma unroll
    for (int j = 0; j < 4; ++j)
      bfr[j] = *reinterpret_cast<const bf16x8*>(&Bbuf[(wc * 64 + j * 16 + lm) * 32 + lkb]);
#pragma unroll
    for (int i = 0; i < 4; ++i)
#pragma unroll
      for (int j = 0; j < 4; ++j)
        acc[i][j] = __builtin_amdgcn_mfma_f32_16x16x32_bf16(af[i], bfr[j], acc[i][j], 0, 0, 0);
    __syncthreads();
  }
}

// ---------------- QKV projection ----------------
__global__ __launch_bounds__(256) void gemm_qkv_kernel(
    const unsigned short* __restrict__ X,
    const unsigned short* __restrict__ Wq, const unsigned short* __restrict__ Wk,
    const unsigned short* __restrict__ Wv,
    const float* __restrict__ bq, const float* __restrict__ bk, const float* __restrict__ bv,
    unsigned short* __restrict__ Qb, unsigned short* __restrict__ Kb,
    unsigned short* __restrict__ Vb) {
  const int m0 = blockIdx.x * 128;
  const int n0 = blockIdx.y * 128;
  const int z  = blockIdx.z;
  const unsigned short* Bw = (z == 0) ? Wq : (z == 1) ? Wk : Wv;
  const float* bias        = (z == 0) ? bq : (z == 1) ? bk : bv;
  unsigned short* Out      = (z == 0) ? Qb : (z == 1) ? Kb : Vb;
  const float scale        = (z == 0) ? SCALE_Q : 1.0f;

  f32x4 acc[4][4];
  gemm_mainloop(X, Bw, m0, n0, acc);

  const int lane = threadIdx.x & 63;
  const int w    = threadIdx.x >> 6;
  const int wr   = w >> 1, wc = w & 1;
  const int lm   = lane & 15, lq = lane >> 4;
#pragma unroll
  for (int j = 0; j < 4; ++j) {
    int col = n0 + wc * 64 + j * 16 + lm;      // E index
    int h = col >> 6, dd = col & 63;
    float bc = bias[col];
#pragma unroll
    for (int i = 0; i < 4; ++i) {
#pragma unroll
      for (int r = 0; r < 4; ++r) {
        int row = m0 + wr * 64 + i * 16 + lq * 4 + r;   // s*B + b
        int s = row >> 1, b = row & 1;
        float v = (acc[i][j][r] + bc) * scale;
        Out[((size_t)(b * NH + h) * S_LEN + s) * DHEAD + dd] = f2b(v);
      }
    }
  }
}

// ---------------- final projection ----------------
__global__ __launch_bounds__(256) void gemm_out_kernel(
    const unsigned short* __restrict__ Ctx, const unsigned short* __restrict__ Wo,
    const float* __restrict__ bo, float* __restrict__ Out) {
  const int m0 = blockIdx.x * 128;
  const int n0 = blockIdx.y * 128;
  f32x4 acc[4][4];
  gemm_mainloop(Ctx, Wo, m0, n0, acc);

  const int lane = threadIdx.x & 63;
  const int w    = threadIdx.x >> 6;
  const int wr   = w >> 1, wc = w & 1;
  const int lm   = lane & 15, lq = lane >> 4;
#pragma unroll
  for (int j = 0; j < 4; ++j) {
    int col = n0 + wc * 64 + j * 16 + lm;
    float bc = bo[col];
#pragma unroll
    for (int i = 0; i < 4; ++i) {
#pragma unroll
      for (int r = 0; r < 4; ++r) {
        int row = m0 + wr * 64 + i * 16 + lq * 4 + r;
        Out[(size_t)row * EMB + col] = acc[i][j][r] + bc;
      }
    }
  }
}

// ---------------- V transpose: [bh][s][d] -> [bh][d][s] ----------------
__global__ __launch_bounds__(256) void transpose_v_kernel(
    const unsigned short* __restrict__ Vb, unsigned short* __restrict__ Vtg) {
  const int bh = blockIdx.x;
  const int kb = blockIdx.y * 64;
  const unsigned short* src = Vb + (size_t)bh * S_LEN * DHEAD;
  unsigned short* dst = Vtg + (size_t)bh * DHEAD * S_LEN;
  __shared__ unsigned short T[64][80];   // pad to 80 (160B rows, 16B aligned)
  const int t = threadIdx.x;
#pragma unroll
  for (int q = 0; q < 2; ++q) {
    int c = t + q * 256;
    int r = c >> 3, j = (c & 7) * 8;
    bf16x8 v = *reinterpret_cast<const bf16x8*>(src + (size_t)(kb + r) * DHEAD + j);
    *reinterpret_cast<bf16x8*>(&T[r][j]) = v;
  }
  __syncthreads();
  // thread t writes row d = t>>2, kv chunk (t&3)*16 .. +16
  int d = t >> 2, kvc = (t & 3) * 16;
  bf16x8 o0, o1;
#pragma unroll
  for (int e = 0; e < 8; ++e) o0[e] = (short)T[kvc + e][d];
#pragma unroll
  for (int e = 0; e < 8; ++e) o1[e] = (short)T[kvc + 8 + e][d];
  *reinterpret_cast<bf16x8*>(dst + (size_t)d * S_LEN + kb + kvc) = o0;
  *reinterpret_cast<bf16x8*>(dst + (size_t)d * S_LEN + kb + kvc + 8) = o1;
}

// ---------------- flash attention, swapped-QK^T ----------------
// grid (B*H=32, S/128=16), 512 threads = 8 waves, wave owns 16 q-rows.
// K staged [kv][d] and V^T staged [d][kv], both 64x64 bf16, XOR-swizzled via
// pre-swizzled global_load_lds source; double-buffered, stage-before-compute.
// S^T = mfma(K, Q): lane holds P^T[kv = ji*16+lq*4+r][q = lm] -> softmax is
// 15 in-lane ops + 2 shfl_xor. P^T -> per-wave LDS (packed b64) -> A-frag b128.
__global__ __launch_bounds__(512) void attn_kernel(
    const unsigned short* __restrict__ Qb, const unsigned short* __restrict__ Kb,
    const unsigned short* __restrict__ Vtg, unsigned short* __restrict__ Ctx) {
  const int bh = blockIdx.x;
  const int q0 = blockIdx.y * 128;
  const int t    = threadIdx.x;
  const int lane = t & 63;
  const int w    = t >> 6;
  const int lm   = lane & 15, lq = lane >> 4;
  const unsigned short* Q  = Qb  + (size_t)bh * S_LEN * DHEAD;
  const unsigned short* K  = Kb  + (size_t)bh * S_LEN * DHEAD;
  const unsigned short* Vt = Vtg + (size_t)bh * DHEAD * S_LEN;   // [d][s]

  __shared__ unsigned short Kl[2][64 * 64];   // [kv][d], swizzled
  __shared__ unsigned short Vl[2][64 * 64];   // [d][kv], swizzled
  __shared__ unsigned short Pl[8][16 * 72];   // per-wave P[q][kv], stride 72

  const int qw = q0 + w * 16;

  // Q = B-operand, held in registers: lane holds Q[q=lm][d = c*32 + lq*8 ..+8]
  bf16x8 aq[2];
#pragma unroll
  for (int c = 0; c < 2; ++c)
    aq[c] = *reinterpret_cast<const bf16x8*>(
        Q + (size_t)(qw + lm) * DHEAD + c * 32 + lq * 8);

  f32x4 zf = {0.0f, 0.0f, 0.0f, 0.0f};
  f32x4 accO[4];                // O[q=lq*4+r][d=ni*16+lm]
#pragma unroll
  for (int ni = 0; ni < 4; ++ni) accO[ni] = zf;
  float m_s = -1e30f, l_s = 0.0f;   // per lane, q = lm (4 redundant copies)

  // stage one K tile + one Vt tile into buffer b (512 chunks of 16B each)
  auto STAGE = [&](int b, int kb) {
    int r = t >> 3, p = t & 7;
    int lc = p ^ (r & 7);
    GLD16(K  + (size_t)(kb + r) * DHEAD + lc * 8,
          (char*)&Kl[b][0] + (size_t)(w * 64) * 16);
    GLD16(Vt + (size_t)r * S_LEN + kb + lc * 8,
          (char*)&Vl[b][0] + (size_t)(w * 64) * 16);
  };

  STAGE(0, 0);
  asm volatile("s_waitcnt vmcnt(0)" ::: "memory");
  __syncthreads();

  int cur = 0;
  const int NT = S_LEN / 64;
  for (int it = 0; it < NT; ++it) {
    if (it + 1 < NT) STAGE(cur ^ 1, (it + 1) * 64);

    // ---- S^T = K Q^T : p4[ji] rows kv = ji*16+lq*4+r, col q = lm ----
    f32x4 p4[4];
#pragma unroll
    for (int ji = 0; ji < 4; ++ji) {
      int rr = ji * 16 + lm;
      bf16x8 k0 = *reinterpret_cast<const bf16x8*>(
          &Kl[cur][rr * 64 + ((lq) ^ (rr & 7)) * 8]);
      bf16x8 k1 = *reinterpret_cast<const bf16x8*>(
          &Kl[cur][rr * 64 + ((4 + lq) ^ (rr & 7)) * 8]);
      f32x4 s0 = __builtin_amdgcn_mfma_f32_16x16x32_bf16(k0, aq[0], zf, 0, 0, 0);
      p4[ji]   = __builtin_amdgcn_mfma_f32_16x16x32_bf16(k1, aq[1], s0, 0, 0, 0);
    }

    // ---- online softmax (per lane, q = lm) ----
    float tm = p4[0][0];
#pragma unroll
    for (int ji = 0; ji < 4; ++ji)
#pragma unroll
      for (int r = 0; r < 4; ++r) tm = fmaxf(tm, p4[ji][r]);
    tm = fmaxf(tm, __shfl_xor(tm, 16));
    tm = fmaxf(tm, __shfl_xor(tm, 32));
    float mn = fmaxf(m_s, tm);
    float sc = __expf(m_s - mn);
    float ps = 0.0f;
#pragma unroll
    for (int ji = 0; ji < 4; ++ji)
#pragma unroll
      for (int r = 0; r < 4; ++r) {
        float e = __expf(p4[ji][r] - mn);
        p4[ji][r] = e;
        ps += e;
      }
    ps += __shfl_xor(ps, 16);
    ps += __shfl_xor(ps, 32);
    l_s = l_s * sc + ps;
    m_s = mn;

    // rescale accO: rows are q = lq*4+r -> fetch sc for that q from lane q
#pragma unroll
    for (int r = 0; r < 4; ++r) {
      float scr = __shfl(sc, lq * 4 + r);
#pragma unroll
      for (int ni = 0; ni < 4; ++ni) accO[ni][r] *= scr;
    }

    // ---- P^T -> per-wave LDS (packed 4 bf16 = b64 per ji) ----
    unsigned short* Pw = &Pl[w][0];
#pragma unroll
    for (int ji = 0; ji < 4; ++ji) {
      uint2 u;
      u.x = (unsigned)f2b(p4[ji][0]) | ((unsigned)f2b(p4[ji][1]) << 16);
      u.y = (unsigned)f2b(p4[ji][2]) | ((unsigned)f2b(p4[ji][3]) << 16);
      *reinterpret_cast<uint2*>(&Pw[lm * 72 + ji * 16 + lq * 4]) = u;
    }

    // ---- O += P V : A = P[q][kv] from LDS, B = Vt[d][kv] swizzled ----
    bf16x8 ap[2];
#pragma unroll
    for (int c = 0; c < 2; ++c)
      ap[c] = *reinterpret_cast<const bf16x8*>(&Pw[lm * 72 + c * 32 + lq * 8]);
#pragma unroll
    for (int ni = 0; ni < 4; ++ni) {
      int dd = ni * 16 + lm;
#pragma unroll
      for (int c = 0; c < 2; ++c) {
        bf16x8 bv = *reinterpret_cast<const bf16x8*>(
            &Vl[cur][dd * 64 + ((c * 4 + lq) ^ (dd & 7)) * 8]);
        accO[ni] = __builtin_amdgcn_mfma_f32_16x16x32_bf16(ap[c], bv, accO[ni], 0, 0, 0);
      }
    }

    asm volatile("s_waitcnt vmcnt(0)" ::: "memory");
    __syncthreads();
    cur ^= 1;
  }

  // ---- epilogue: normalize, write ctx [S,B,E] bf16 ----
  const int b = bh >> 4, h = bh & 15;
#pragma unroll
  for (int r = 0; r < 4; ++r) {
    float rl = 1.0f / __shfl(l_s, lq * 4 + r);
    int srow = qw + lq * 4 + r;
    size_t rowbase = ((size_t)srow * BATCH + b) * EMB + (size_t)h * 64;
#pragma unroll
    for (int ni = 0; ni < 4; ++ni)
      Ctx[rowbase + ni * 16 + lm] = f2b(accO[ni][r] * rl);
  }
}

// ---------------- launch ----------------
extern "C" void kernel_launch(void* const* d_in, const int* in_sizes, int n_in,
                              void* d_out, int out_size, void* d_ws, size_t ws_size,
                              hipStream_t stream) {
  const float* query = (const float*)d_in[0];
  const float* wq = (const float*)d_in[1];
  const float* bq = (const float*)d_in[2];
  const float* wk = (const float*)d_in[3];
  const float* bk = (const float*)d_in[4];
  const float* wv = (const float*)d_in[5];
  const float* bv = (const float*)d_in[6];
  const float* wo = (const float*)d_in[7];
  const float* bo = (const float*)d_in[8];
  float* out = (float*)d_out;

  unsigned short* p = (unsigned short*)d_ws;
  unsigned short* Xbf = p;                        p += (size_t)ROWS * EMB;   // 8 MB
  unsigned short* Wqb = p;                        p += (size_t)EMB * EMB;
  unsigned short* Wkb = p;                        p += (size_t)EMB * EMB;
  unsigned short* Wvb = p;                        p += (size_t)EMB * EMB;
  unsigned short* Wob = p;                        p += (size_t)EMB * EMB;
  unsigned short* Qb  = p;                        p += (size_t)ROWS * EMB;   // [B,H,S,DH]
  unsigned short* Kb  = p;                        p += (size_t)ROWS * EMB;
  unsigned short* Vb  = p;                        p += (size_t)ROWS * EMB;
  unsigned short* Ctx = p;                        p += (size_t)ROWS * EMB;
  unsigned short* Vtg = Xbf;   // reuse Xbf after gemm_qkv consumed it

  cvt_kernel<<<ROWS * EMB / 8 / 256, 256, 0, stream>>>(query, Xbf);
  cvt4_kernel<<<dim3(EMB * EMB / 8 / 256, 4), 256, 0, stream>>>(
      wq, wk, wv, wo, Wqb, Wkb, Wvb, Wob);
  gemm_qkv_kernel<<<dim3(ROWS / 128, EMB / 128, 3), 256, 0, stream>>>(
      Xbf, Wqb, Wkb, Wvb, bq, bk, bv, Qb, Kb, Vb);
  transpose_v_kernel<<<dim3(BATCH * NH, S_LEN / 64), 256, 0, stream>>>(Vb, Vtg);
  attn_kernel<<<dim3(BATCH * NH, S_LEN / 128), 512, 0, stream>>>(Qb, Kb, Vtg, Ctx);
  gemm_out_kernel<<<dim3(ROWS / 128, EMB / 128), 256, 0, stream>>>(Ctx, Wob, bo, out);
}

// Round 4
// 222.555 us; speedup vs baseline: 1.5224x; 1.0252x over previous
//
#include <hip/hip_runtime.h>
#include <hip/hip_bf16.h>
#include <stdint.h>

// Problem constants
#define S_LEN 2048
#define BATCH 2
#define EMB   1024
#define NH    16
#define DHEAD 64
#define ROWS  (S_LEN*BATCH)   // 4096
// DH^-0.5 * log2(e): scores produced in log2 domain so softmax uses v_exp_f32
#define SCALE_Q 0.18033688011112042f
#define DEFER_THR 11.0f       // log2-domain defer-max threshold (P <= 2^11)

typedef __attribute__((ext_vector_type(8))) short bf16x8;   // 8 bf16 in 4 VGPRs
typedef __attribute__((ext_vector_type(4))) float f32x4;

typedef const __attribute__((address_space(1))) void* gas_ptr;
typedef __attribute__((address_space(3))) void* las_ptr;
// async global->LDS, 16B per lane, dest = wave-uniform base + lane*16
#define GLD16(g, l) __builtin_amdgcn_global_load_lds((gas_ptr)(g), (las_ptr)(l), 16, 0, 0)

__device__ __forceinline__ unsigned short f2b(float f) {
  union { float f; unsigned int u; } v; v.f = f;
  unsigned int u = v.u;
  unsigned int r = (u + 0x7FFFu + ((u >> 16) & 1u)) >> 16;  // RNE
  return (unsigned short)r;
}

__device__ __forceinline__ unsigned cvt_pk_bf16(float lo, float hi) {
  unsigned r;
  asm("v_cvt_pk_bf16_f32 %0, %1, %2" : "=v"(r) : "v"(lo), "v"(hi));
  return r;
}

// ---------------- fp32 -> bf16 conversion ----------------
__device__ __forceinline__ void cvt8(const float* __restrict__ s,
                                     unsigned short* __restrict__ d, size_t i) {
  float4 a = *reinterpret_cast<const float4*>(s + i);
  float4 b = *reinterpret_cast<const float4*>(s + i + 4);
  uint4 o;
  o.x = (unsigned)f2b(a.x) | ((unsigned)f2b(a.y) << 16);
  o.y = (unsigned)f2b(a.z) | ((unsigned)f2b(a.w) << 16);
  o.z = (unsigned)f2b(b.x) | ((unsigned)f2b(b.y) << 16);
  o.w = (unsigned)f2b(b.z) | ((unsigned)f2b(b.w) << 16);
  *reinterpret_cast<uint4*>(d + i) = o;
}

__global__ __launch_bounds__(256) void cvt_kernel(const float* __restrict__ s,
                                                  unsigned short* __restrict__ d) {
  size_t i = ((size_t)blockIdx.x * 256 + threadIdx.x) * 8;
  cvt8(s, d, i);
}

__global__ __launch_bounds__(256) void cvt4_kernel(
    const float* __restrict__ s0, const float* __restrict__ s1,
    const float* __restrict__ s2, const float* __restrict__ s3,
    unsigned short* __restrict__ d0, unsigned short* __restrict__ d1,
    unsigned short* __restrict__ d2, unsigned short* __restrict__ d3) {
  const float* s; unsigned short* d;
  switch (blockIdx.y) {
    case 0:  s = s0; d = d0; break;
    case 1:  s = s1; d = d1; break;
    case 2:  s = s2; d = d2; break;
    default: s = s3; d = d3; break;
  }
  size_t i = ((size_t)blockIdx.x * 256 + threadIdx.x) * 8;
  cvt8(s, d, i);
}

// ---------------- GEMM mainloop (C = A * B^T), 128x128 tile, BK=64 ----------------
// 2-phase double-buffered: STAGE(next) issued before ds_read+MFMA(cur), single
// vmcnt(0)+barrier per K-tile. LDS XOR-swizzled both-sides (16B slot ^ row&7):
// read bank = slot*4 -> 2-way max (free). 4 waves (2x2), each 64x64 output.
__device__ __forceinline__ void gemm_mainloop(const unsigned short* __restrict__ A,
                                              const unsigned short* __restrict__ Bw,
                                              int m0, int n0, f32x4 acc[4][4]) {
  __shared__ unsigned short Ab[2][128 * 64];
  __shared__ unsigned short Bb[2][128 * 64];
  const int t    = threadIdx.x;
  const int lane = t & 63;
  const int w    = t >> 6;
  const int wr   = w >> 1, wc = w & 1;
  const int lm   = lane & 15;
  const int lq   = lane >> 4;

  f32x4 zf = {0.0f, 0.0f, 0.0f, 0.0f};
#pragma unroll
  for (int i = 0; i < 4; ++i)
#pragma unroll
    for (int j = 0; j < 4; ++j) acc[i][j] = zf;

  // stage 128x64 A-tile + B-tile into buffer b: 1024 16B chunks each,
  // thread t handles chunks t+q*256; chunk c -> row c>>3, phys slot c&7
  // holding logical column-chunk (c&7)^(row&7) (inverse swizzle on source).
  auto STAGE = [&](int b, int k0) {
#pragma unroll
    for (int q = 0; q < 4; ++q) {
      int c = t + q * 256;
      int r = c >> 3, ci = c & 7;
      int lc = ci ^ (r & 7);
      GLD16(A  + (size_t)(m0 + r) * EMB + k0 + lc * 8,
            (char*)&Ab[b][0] + (size_t)(q * 256 + w * 64) * 16);
      GLD16(Bw + (size_t)(n0 + r) * EMB + k0 + lc * 8,
            (char*)&Bb[b][0] + (size_t)(q * 256 + w * 64) * 16);
    }
  };

  STAGE(0, 0);
  asm volatile("s_waitcnt vmcnt(0)" ::: "memory");
  __syncthreads();

  int cur = 0;
  const int NT = EMB / 64;
  for (int it = 0; it < NT; ++it) {
    if (it + 1 < NT) STAGE(cur ^ 1, (it + 1) * 64);

#pragma unroll
    for (int kk = 0; kk < 2; ++kk) {
      bf16x8 af[4], bfr[4];
#pragma unroll
      for (int i = 0; i < 4; ++i) {
        int ra = wr * 64 + i * 16 + lm;
        af[i] = *reinterpret_cast<const bf16x8*>(
            &Ab[cur][ra * 64 + ((kk * 4 + lq) ^ (ra & 7)) * 8]);
      }
#pragma unroll
      for (int j = 0; j < 4; ++j) {
        int rb = wc * 64 + j * 16 + lm;
        bfr[j] = *reinterpret_cast<const bf16x8*>(
            &Bb[cur][rb * 64 + ((kk * 4 + lq) ^ (rb & 7)) * 8]);
      }
#pragma unroll
      for (int i = 0; i < 4; ++i)
#pragma unroll
        for (int j = 0; j < 4; ++j)
          acc[i][j] = __builtin_amdgcn_mfma_f32_16x16x32_bf16(af[i], bfr[j], acc[i][j], 0, 0, 0);
    }

    asm volatile("s_waitcnt vmcnt(0)" ::: "memory");
    __syncthreads();
    cur ^= 1;
  }
}

// ---------------- QKV projection ----------------
__global__ __launch_bounds__(256) void gemm_qkv_kernel(
    const unsigned short* __restrict__ X,
    const unsigned short* __restrict__ Wq, const unsigned short* __restrict__ Wk,
    const unsigned short* __restrict__ Wv,
    const float* __restrict__ bq, const float* __restrict__ bk, const float* __restrict__ bv,
    unsigned short* __restrict__ Qb, unsigned short* __restrict__ Kb,
    unsigned short* __restrict__ Vb) {
  const int m0 = blockIdx.x * 128;
  const int n0 = blockIdx.y * 128;
  const int z  = blockIdx.z;
  const unsigned short* Bw = (z == 0) ? Wq : (z == 1) ? Wk : Wv;
  const float* bias        = (z == 0) ? bq : (z == 1) ? bk : bv;
  unsigned short* Out      = (z == 0) ? Qb : (z == 1) ? Kb : Vb;
  const float scale        = (z == 0) ? SCALE_Q : 1.0f;

  f32x4 acc[4][4];
  gemm_mainloop(X, Bw, m0, n0, acc);

  const int lane = threadIdx.x & 63;
  const int w    = threadIdx.x >> 6;
  const int wr   = w >> 1, wc = w & 1;
  const int lm   = lane & 15, lq = lane >> 4;
#pragma unroll
  for (int j = 0; j < 4; ++j) {
    int col = n0 + wc * 64 + j * 16 + lm;      // E index
    int h = col >> 6, dd = col & 63;
    float bc = bias[col];
#pragma unroll
    for (int i = 0; i < 4; ++i) {
#pragma unroll
      for (int r = 0; r < 4; ++r) {
        int row = m0 + wr * 64 + i * 16 + lq * 4 + r;   // s*B + b
        int s = row >> 1, b = row & 1;
        float v = (acc[i][j][r] + bc) * scale;
        Out[((size_t)(b * NH + h) * S_LEN + s) * DHEAD + dd] = f2b(v);
      }
    }
  }
}

// ---------------- final projection ----------------
__global__ __launch_bounds__(256) void gemm_out_kernel(
    const unsigned short* __restrict__ Ctx, const unsigned short* __restrict__ Wo,
    const float* __restrict__ bo, float* __restrict__ Out) {
  const int m0 = blockIdx.x * 128;
  const int n0 = blockIdx.y * 128;
  f32x4 acc[4][4];
  gemm_mainloop(Ctx, Wo, m0, n0, acc);

  const int lane = threadIdx.x & 63;
  const int w    = threadIdx.x >> 6;
  const int wr   = w >> 1, wc = w & 1;
  const int lm   = lane & 15, lq = lane >> 4;
#pragma unroll
  for (int j = 0; j < 4; ++j) {
    int col = n0 + wc * 64 + j * 16 + lm;
    float bc = bo[col];
#pragma unroll
    for (int i = 0; i < 4; ++i) {
#pragma unroll
      for (int r = 0; r < 4; ++r) {
        int row = m0 + wr * 64 + i * 16 + lq * 4 + r;
        Out[(size_t)row * EMB + col] = acc[i][j][r] + bc;
      }
    }
  }
}

// ---------------- V transpose: [bh][s][d] -> [bh][d][s] ----------------
__global__ __launch_bounds__(256) void transpose_v_kernel(
    const unsigned short* __restrict__ Vb, unsigned short* __restrict__ Vtg) {
  const int bh = blockIdx.x;
  const int kb = blockIdx.y * 64;
  const unsigned short* src = Vb + (size_t)bh * S_LEN * DHEAD;
  unsigned short* dst = Vtg + (size_t)bh * DHEAD * S_LEN;
  __shared__ unsigned short T[64][80];
  const int t = threadIdx.x;
#pragma unroll
  for (int q = 0; q < 2; ++q) {
    int c = t + q * 256;
    int r = c >> 3, j = (c & 7) * 8;
    bf16x8 v = *reinterpret_cast<const bf16x8*>(src + (size_t)(kb + r) * DHEAD + j);
    *reinterpret_cast<bf16x8*>(&T[r][j]) = v;
  }
  __syncthreads();
  int d = t >> 2, kvc = (t & 3) * 16;
  bf16x8 o0, o1;
#pragma unroll
  for (int e = 0; e < 8; ++e) o0[e] = (short)T[kvc + e][d];
#pragma unroll
  for (int e = 0; e < 8; ++e) o1[e] = (short)T[kvc + 8 + e][d];
  *reinterpret_cast<bf16x8*>(dst + (size_t)d * S_LEN + kb + kvc) = o0;
  *reinterpret_cast<bf16x8*>(dst + (size_t)d * S_LEN + kb + kvc + 8) = o1;
}

// ---------------- flash attention, swapped-QK^T, log2-domain softmax ----------------
__global__ __launch_bounds__(512) void attn_kernel(
    const unsigned short* __restrict__ Qb, const unsigned short* __restrict__ Kb,
    const unsigned short* __restrict__ Vtg, unsigned short* __restrict__ Ctx) {
  const int bh = blockIdx.x;
  const int q0 = blockIdx.y * 128;
  const int t    = threadIdx.x;
  const int lane = t & 63;
  const int w    = t >> 6;
  const int lm   = lane & 15, lq = lane >> 4;
  const unsigned short* Q  = Qb  + (size_t)bh * S_LEN * DHEAD;
  const unsigned short* K  = Kb  + (size_t)bh * S_LEN * DHEAD;
  const unsigned short* Vt = Vtg + (size_t)bh * DHEAD * S_LEN;   // [d][s]

  __shared__ unsigned short Kl[2][64 * 64];   // [kv][d], swizzled
  __shared__ unsigned short Vl[2][64 * 64];   // [d][kv], swizzled
  __shared__ unsigned short Pl[8][16 * 72];   // per-wave P[q][kv], stride 72

  const int qw = q0 + w * 16;

  bf16x8 aq[2];
#pragma unroll
  for (int c = 0; c < 2; ++c)
    aq[c] = *reinterpret_cast<const bf16x8*>(
        Q + (size_t)(qw + lm) * DHEAD + c * 32 + lq * 8);

  f32x4 zf = {0.0f, 0.0f, 0.0f, 0.0f};
  f32x4 accO[4];                // O[q=lq*4+r][d=ni*16+lm]
#pragma unroll
  for (int ni = 0; ni < 4; ++ni) accO[ni] = zf;
  float m_s = -1e30f, l_s = 0.0f;   // per lane, q = lm

  auto STAGE = [&](int b, int kb) {
    int r = t >> 3, p = t & 7;
    int lc = p ^ (r & 7);
    GLD16(K  + (size_t)(kb + r) * DHEAD + lc * 8,
          (char*)&Kl[b][0] + (size_t)(w * 64) * 16);
    GLD16(Vt + (size_t)r * S_LEN + kb + lc * 8,
          (char*)&Vl[b][0] + (size_t)(w * 64) * 16);
  };

  STAGE(0, 0);
  asm volatile("s_waitcnt vmcnt(0)" ::: "memory");
  __syncthreads();

  int cur = 0;
  const int NT = S_LEN / 64;
  for (int it = 0; it < NT; ++it) {
    if (it + 1 < NT) STAGE(cur ^ 1, (it + 1) * 64);

    // ---- S^T = K Q^T (log2 domain): p4[ji] rows kv = ji*16+lq*4+r, col q = lm
    f32x4 p4[4];
    __builtin_amdgcn_s_setprio(1);
#pragma unroll
    for (int ji = 0; ji < 4; ++ji) {
      int rr = ji * 16 + lm;
      bf16x8 k0 = *reinterpret_cast<const bf16x8*>(
          &Kl[cur][rr * 64 + ((lq) ^ (rr & 7)) * 8]);
      bf16x8 k1 = *reinterpret_cast<const bf16x8*>(
          &Kl[cur][rr * 64 + ((4 + lq) ^ (rr & 7)) * 8]);
      f32x4 s0 = __builtin_amdgcn_mfma_f32_16x16x32_bf16(k0, aq[0], zf, 0, 0, 0);
      p4[ji]   = __builtin_amdgcn_mfma_f32_16x16x32_bf16(k1, aq[1], s0, 0, 0, 0);
    }
    __builtin_amdgcn_s_setprio(0);

    // ---- online softmax (per lane, q = lm), max3-friendly tree ----
    float t0 = fmaxf(fmaxf(p4[0][0], p4[0][1]), fmaxf(p4[0][2], p4[0][3]));
    float t1 = fmaxf(fmaxf(p4[1][0], p4[1][1]), fmaxf(p4[1][2], p4[1][3]));
    float t2 = fmaxf(fmaxf(p4[2][0], p4[2][1]), fmaxf(p4[2][2], p4[2][3]));
    float t3 = fmaxf(fmaxf(p4[3][0], p4[3][1]), fmaxf(p4[3][2], p4[3][3]));
    float tm = fmaxf(fmaxf(t0, t1), fmaxf(t2, t3));
    tm = fmaxf(tm, __shfl_xor(tm, 16));
    tm = fmaxf(tm, __shfl_xor(tm, 32));

    // defer-max: only rescale when the tile max beats running max by > THR
    if (!__all(tm - m_s <= DEFER_THR)) {
      float mn = fmaxf(m_s, tm);
      float sc = exp2f(m_s - mn);
      l_s *= sc;
      m_s = mn;
#pragma unroll
      for (int r = 0; r < 4; ++r) {
        float scr = __shfl(sc, lq * 4 + r);
#pragma unroll
        for (int ni = 0; ni < 4; ++ni) accO[ni][r] *= scr;
      }
    }

    float ps = 0.0f;
#pragma unroll
    for (int ji = 0; ji < 4; ++ji)
#pragma unroll
      for (int r = 0; r < 4; ++r) {
        float e = exp2f(p4[ji][r] - m_s);
        p4[ji][r] = e;
        ps += e;
      }
    ps += __shfl_xor(ps, 16);
    ps += __shfl_xor(ps, 32);
    l_s += ps;

    // ---- P^T -> per-wave LDS (v_cvt_pk_bf16_f32 packing) ----
    unsigned short* Pw = &Pl[w][0];
#pragma unroll
    for (int ji = 0; ji < 4; ++ji) {
      uint2 u;
      u.x = cvt_pk_bf16(p4[ji][0], p4[ji][1]);
      u.y = cvt_pk_bf16(p4[ji][2], p4[ji][3]);
      *reinterpret_cast<uint2*>(&Pw[lm * 72 + ji * 16 + lq * 4]) = u;
    }

    // ---- O += P V ----
    bf16x8 ap[2];
#pragma unroll
    for (int c = 0; c < 2; ++c)
      ap[c] = *reinterpret_cast<const bf16x8*>(&Pw[lm * 72 + c * 32 + lq * 8]);
    __builtin_amdgcn_s_setprio(1);
#pragma unroll
    for (int ni = 0; ni < 4; ++ni) {
      int dd = ni * 16 + lm;
#pragma unroll
      for (int c = 0; c < 2; ++c) {
        bf16x8 bv = *reinterpret_cast<const bf16x8*>(
            &Vl[cur][dd * 64 + ((c * 4 + lq) ^ (dd & 7)) * 8]);
        accO[ni] = __builtin_amdgcn_mfma_f32_16x16x32_bf16(ap[c], bv, accO[ni], 0, 0, 0);
      }
    }
    __builtin_amdgcn_s_setprio(0);

    asm volatile("s_waitcnt vmcnt(0)" ::: "memory");
    __syncthreads();
    cur ^= 1;
  }

  // ---- epilogue: normalize, write ctx [S,B,E] bf16 ----
  const int b = bh >> 4, h = bh & 15;
#pragma unroll
  for (int r = 0; r < 4; ++r) {
    float rl = 1.0f / __shfl(l_s, lq * 4 + r);
    int srow = qw + lq * 4 + r;
    size_t rowbase = ((size_t)srow * BATCH + b) * EMB + (size_t)h * 64;
#pragma unroll
    for (int ni = 0; ni < 4; ++ni)
      Ctx[rowbase + ni * 16 + lm] = f2b(accO[ni][r] * rl);
  }
}

// ---------------- launch ----------------
extern "C" void kernel_launch(void* const* d_in, const int* in_sizes, int n_in,
                              void* d_out, int out_size, void* d_ws, size_t ws_size,
                              hipStream_t stream) {
  const float* query = (const float*)d_in[0];
  const float* wq = (const float*)d_in[1];
  const float* bq = (const float*)d_in[2];
  const float* wk = (const float*)d_in[3];
  const float* bk = (const float*)d_in[4];
  const float* wv = (const float*)d_in[5];
  const float* bv = (const float*)d_in[6];
  const float* wo = (const float*)d_in[7];
  const float* bo = (const float*)d_in[8];
  float* out = (float*)d_out;

  unsigned short* p = (unsigned short*)d_ws;
  unsigned short* Xbf = p;                        p += (size_t)ROWS * EMB;
  unsigned short* Wqb = p;                        p += (size_t)EMB * EMB;
  unsigned short* Wkb = p;                        p += (size_t)EMB * EMB;
  unsigned short* Wvb = p;                        p += (size_t)EMB * EMB;
  unsigned short* Wob = p;                        p += (size_t)EMB * EMB;
  unsigned short* Qb  = p;                        p += (size_t)ROWS * EMB;   // [B,H,S,DH]
  unsigned short* Kb  = p;                        p += (size_t)ROWS * EMB;
  unsigned short* Vb  = p;                        p += (size_t)ROWS * EMB;
  unsigned short* Ctx = p;                        p += (size_t)ROWS * EMB;
  unsigned short* Vtg = Xbf;   // reuse Xbf after gemm_qkv consumed it

  cvt_kernel<<<ROWS * EMB / 8 / 256, 256, 0, stream>>>(query, Xbf);
  cvt4_kernel<<<dim3(EMB * EMB / 8 / 256, 4), 256, 0, stream>>>(
      wq, wk, wv, wo, Wqb, Wkb, Wvb, Wob);
  gemm_qkv_kernel<<<dim3(ROWS / 128, EMB / 128, 3), 256, 0, stream>>>(
      Xbf, Wqb, Wkb, Wvb, bq, bk, bv, Qb, Kb, Vb);
  transpose_v_kernel<<<dim3(BATCH * NH, S_LEN / 64), 256, 0, stream>>>(Vb, Vtg);
  attn_kernel<<<dim3(BATCH * NH, S_LEN / 128), 512, 0, stream>>>(Qb, Kb, Vtg, Ctx);
  gemm_out_kernel<<<dim3(ROWS / 128, EMB / 128), 256, 0, stream>>>(Ctx, Wob, bo, out);
}

// Round 5
// 222.362 us; speedup vs baseline: 1.5237x; 1.0009x over previous
//
#include <hip/hip_runtime.h>
#include <hip/hip_bf16.h>
#include <stdint.h>

// Problem constants
#define S_LEN 2048
#define BATCH 2
#define EMB   1024
#define NH    16
#define DHEAD 64
#define ROWS  (S_LEN*BATCH)   // 4096
// DH^-0.5 * log2(e): scores produced in log2 domain so softmax uses v_exp_f32
#define SCALE_Q 0.18033688011112042f
#define DEFER_THR 11.0f       // log2-domain defer-max threshold (P <= 2^11)

typedef __attribute__((ext_vector_type(8))) short bf16x8;   // 8 bf16 in 4 VGPRs
typedef __attribute__((ext_vector_type(4))) float f32x4;

typedef const __attribute__((address_space(1))) void* gas_ptr;
typedef __attribute__((address_space(3))) void* las_ptr;
// async global->LDS, 16B per lane, dest = wave-uniform base + lane*16
#define GLD16(g, l) __builtin_amdgcn_global_load_lds((gas_ptr)(g), (las_ptr)(l), 16, 0, 0)

__device__ __forceinline__ unsigned short f2b(float f) {
  union { float f; unsigned int u; } v; v.f = f;
  unsigned int u = v.u;
  unsigned int r = (u + 0x7FFFu + ((u >> 16) & 1u)) >> 16;  // RNE
  return (unsigned short)r;
}

__device__ __forceinline__ unsigned cvt_pk_bf16(float lo, float hi) {
  unsigned r;
  asm("v_cvt_pk_bf16_f32 %0, %1, %2" : "=v"(r) : "v"(lo), "v"(hi));
  return r;
}

// ---------------- fp32 -> bf16 conversion ----------------
__device__ __forceinline__ void cvt8(const float* __restrict__ s,
                                     unsigned short* __restrict__ d, size_t i) {
  float4 a = *reinterpret_cast<const float4*>(s + i);
  float4 b = *reinterpret_cast<const float4*>(s + i + 4);
  uint4 o;
  o.x = (unsigned)f2b(a.x) | ((unsigned)f2b(a.y) << 16);
  o.y = (unsigned)f2b(a.z) | ((unsigned)f2b(a.w) << 16);
  o.z = (unsigned)f2b(b.x) | ((unsigned)f2b(b.y) << 16);
  o.w = (unsigned)f2b(b.z) | ((unsigned)f2b(b.w) << 16);
  *reinterpret_cast<uint4*>(d + i) = o;
}

__global__ __launch_bounds__(256) void cvt_kernel(const float* __restrict__ s,
                                                  unsigned short* __restrict__ d) {
  size_t i = ((size_t)blockIdx.x * 256 + threadIdx.x) * 8;
  cvt8(s, d, i);
}

__global__ __launch_bounds__(256) void cvt4_kernel(
    const float* __restrict__ s0, const float* __restrict__ s1,
    const float* __restrict__ s2, const float* __restrict__ s3,
    unsigned short* __restrict__ d0, unsigned short* __restrict__ d1,
    unsigned short* __restrict__ d2, unsigned short* __restrict__ d3) {
  const float* s; unsigned short* d;
  switch (blockIdx.y) {
    case 0:  s = s0; d = d0; break;
    case 1:  s = s1; d = d1; break;
    case 2:  s = s2; d = d2; break;
    default: s = s3; d = d3; break;
  }
  size_t i = ((size_t)blockIdx.x * 256 + threadIdx.x) * 8;
  cvt8(s, d, i);
}

// ---------------- GEMM mainloop (C = A * B^T), 128x128 tile, BK=64 ----------------
// m97 structure: SINGLE-buffered 32 KB LDS (~3 blocks/CU), per K-step:
// stage -> vmcnt0+barrier -> ds_read+MFMA -> barrier. Cross-block TLP hides
// the drain (m97: 874-912 TF). XOR swizzle kept (free).
__device__ __forceinline__ void gemm_mainloop(const unsigned short* __restrict__ A,
                                              const unsigned short* __restrict__ Bw,
                                              int m0, int n0, f32x4 acc[4][4]) {
  __shared__ unsigned short Ab[128 * 64];
  __shared__ unsigned short Bb[128 * 64];
  const int t    = threadIdx.x;
  const int lane = t & 63;
  const int w    = t >> 6;
  const int wr   = w >> 1, wc = w & 1;
  const int lm   = lane & 15;
  const int lq   = lane >> 4;

  f32x4 zf = {0.0f, 0.0f, 0.0f, 0.0f};
#pragma unroll
  for (int i = 0; i < 4; ++i)
#pragma unroll
    for (int j = 0; j < 4; ++j) acc[i][j] = zf;

  for (int k0 = 0; k0 < EMB; k0 += 64) {
    // stage 128x64 A-tile + B-tile: 1024 16B chunks each; chunk c -> row c>>3,
    // phys slot c&7 holds logical column-chunk (c&7)^(row&7) (inverse swizzle).
#pragma unroll
    for (int q = 0; q < 4; ++q) {
      int c = t + q * 256;
      int r = c >> 3, ci = c & 7;
      int lc = ci ^ (r & 7);
      GLD16(A  + (size_t)(m0 + r) * EMB + k0 + lc * 8,
            (char*)&Ab[0] + (size_t)(q * 256 + w * 64) * 16);
      GLD16(Bw + (size_t)(n0 + r) * EMB + k0 + lc * 8,
            (char*)&Bb[0] + (size_t)(q * 256 + w * 64) * 16);
    }
    asm volatile("s_waitcnt vmcnt(0)" ::: "memory");
    __syncthreads();

#pragma unroll
    for (int kk = 0; kk < 2; ++kk) {
      bf16x8 af[4], bfr[4];
#pragma unroll
      for (int i = 0; i < 4; ++i) {
        int ra = wr * 64 + i * 16 + lm;
        af[i] = *reinterpret_cast<const bf16x8*>(
            &Ab[ra * 64 + ((kk * 4 + lq) ^ (ra & 7)) * 8]);
      }
#pragma unroll
      for (int j = 0; j < 4; ++j) {
        int rb = wc * 64 + j * 16 + lm;
        bfr[j] = *reinterpret_cast<const bf16x8*>(
            &Bb[rb * 64 + ((kk * 4 + lq) ^ (rb & 7)) * 8]);
      }
#pragma unroll
      for (int i = 0; i < 4; ++i)
#pragma unroll
        for (int j = 0; j < 4; ++j)
          acc[i][j] = __builtin_amdgcn_mfma_f32_16x16x32_bf16(af[i], bfr[j], acc[i][j], 0, 0, 0);
    }
    __syncthreads();
  }
}

// ---------------- QKV projection ----------------
__global__ __launch_bounds__(256) void gemm_qkv_kernel(
    const unsigned short* __restrict__ X,
    const unsigned short* __restrict__ Wq, const unsigned short* __restrict__ Wk,
    const unsigned short* __restrict__ Wv,
    const float* __restrict__ bq, const float* __restrict__ bk, const float* __restrict__ bv,
    unsigned short* __restrict__ Qb, unsigned short* __restrict__ Kb,
    unsigned short* __restrict__ Vb) {
  const int m0 = blockIdx.x * 128;
  const int n0 = blockIdx.y * 128;
  const int z  = blockIdx.z;
  const unsigned short* Bw = (z == 0) ? Wq : (z == 1) ? Wk : Wv;
  const float* bias        = (z == 0) ? bq : (z == 1) ? bk : bv;
  unsigned short* Out      = (z == 0) ? Qb : (z == 1) ? Kb : Vb;
  const float scale        = (z == 0) ? SCALE_Q : 1.0f;

  f32x4 acc[4][4];
  gemm_mainloop(X, Bw, m0, n0, acc);

  const int lane = threadIdx.x & 63;
  const int w    = threadIdx.x >> 6;
  const int wr   = w >> 1, wc = w & 1;
  const int lm   = lane & 15, lq = lane >> 4;
#pragma unroll
  for (int j = 0; j < 4; ++j) {
    int col = n0 + wc * 64 + j * 16 + lm;      // E index
    int h = col >> 6, dd = col & 63;
    float bc = bias[col];
#pragma unroll
    for (int i = 0; i < 4; ++i) {
#pragma unroll
      for (int r = 0; r < 4; ++r) {
        int row = m0 + wr * 64 + i * 16 + lq * 4 + r;   // s*B + b
        int s = row >> 1, b = row & 1;
        float v = (acc[i][j][r] + bc) * scale;
        Out[((size_t)(b * NH + h) * S_LEN + s) * DHEAD + dd] = f2b(v);
      }
    }
  }
}

// ---------------- final projection ----------------
__global__ __launch_bounds__(256) void gemm_out_kernel(
    const unsigned short* __restrict__ Ctx, const unsigned short* __restrict__ Wo,
    const float* __restrict__ bo, float* __restrict__ Out) {
  const int m0 = blockIdx.x * 128;
  const int n0 = blockIdx.y * 128;
  f32x4 acc[4][4];
  gemm_mainloop(Ctx, Wo, m0, n0, acc);

  const int lane = threadIdx.x & 63;
  const int w    = threadIdx.x >> 6;
  const int wr   = w >> 1, wc = w & 1;
  const int lm   = lane & 15, lq = lane >> 4;
#pragma unroll
  for (int j = 0; j < 4; ++j) {
    int col = n0 + wc * 64 + j * 16 + lm;
    float bc = bo[col];
#pragma unroll
    for (int i = 0; i < 4; ++i) {
#pragma unroll
      for (int r = 0; r < 4; ++r) {
        int row = m0 + wr * 64 + i * 16 + lq * 4 + r;
        Out[(size_t)row * EMB + col] = acc[i][j][r] + bc;
      }
    }
  }
}

// ---------------- V transpose: [bh][s][d] -> [bh][d][s] ----------------
__global__ __launch_bounds__(256) void transpose_v_kernel(
    const unsigned short* __restrict__ Vb, unsigned short* __restrict__ Vtg) {
  const int bh = blockIdx.x;
  const int kb = blockIdx.y * 64;
  const unsigned short* src = Vb + (size_t)bh * S_LEN * DHEAD;
  unsigned short* dst = Vtg + (size_t)bh * DHEAD * S_LEN;
  __shared__ unsigned short T[64][80];
  const int t = threadIdx.x;
#pragma unroll
  for (int q = 0; q < 2; ++q) {
    int c = t + q * 256;
    int r = c >> 3, j = (c & 7) * 8;
    bf16x8 v = *reinterpret_cast<const bf16x8*>(src + (size_t)(kb + r) * DHEAD + j);
    *reinterpret_cast<bf16x8*>(&T[r][j]) = v;
  }
  __syncthreads();
  int d = t >> 2, kvc = (t & 3) * 16;
  bf16x8 o0, o1;
#pragma unroll
  for (int e = 0; e < 8; ++e) o0[e] = (short)T[kvc + e][d];
#pragma unroll
  for (int e = 0; e < 8; ++e) o1[e] = (short)T[kvc + 8 + e][d];
  *reinterpret_cast<bf16x8*>(dst + (size_t)d * S_LEN + kb + kvc) = o0;
  *reinterpret_cast<bf16x8*>(dst + (size_t)d * S_LEN + kb + kvc + 8) = o1;
}

// ---------------- flash attention, swapped-QK^T, log2-domain softmax ----------------
// 2-deep counted-vmcnt pipeline with RAW s_barrier (no compiler vmcnt(0) drain):
// prologue stages tiles 0,1; iter t waits vmcnt(2) (own tile-t loads done),
// barrier, computes, lgkmcnt(0)+sched_barrier+barrier, stages tile t+2.
// Loads for tile t+1 stay in flight across the whole compute of tile t.
__global__ __launch_bounds__(512) void attn_kernel(
    const unsigned short* __restrict__ Qb, const unsigned short* __restrict__ Kb,
    const unsigned short* __restrict__ Vtg, unsigned short* __restrict__ Ctx) {
  const int bh = blockIdx.x;
  const int q0 = blockIdx.y * 128;
  const int t    = threadIdx.x;
  const int lane = t & 63;
  const int w    = t >> 6;
  const int lm   = lane & 15, lq = lane >> 4;
  const unsigned short* Q  = Qb  + (size_t)bh * S_LEN * DHEAD;
  const unsigned short* K  = Kb  + (size_t)bh * S_LEN * DHEAD;
  const unsigned short* Vt = Vtg + (size_t)bh * DHEAD * S_LEN;   // [d][s]

  __shared__ unsigned short Kl[2][64 * 64];   // [kv][d], swizzled
  __shared__ unsigned short Vl[2][64 * 64];   // [d][kv], swizzled
  __shared__ unsigned short Pl[8][16 * 72];   // per-wave P[q][kv], stride 72

  const int qw = q0 + w * 16;

  bf16x8 aq[2];
#pragma unroll
  for (int c = 0; c < 2; ++c)
    aq[c] = *reinterpret_cast<const bf16x8*>(
        Q + (size_t)(qw + lm) * DHEAD + c * 32 + lq * 8);

  f32x4 zf = {0.0f, 0.0f, 0.0f, 0.0f};
  f32x4 accO[4];                // O[q=lq*4+r][d=ni*16+lm]
#pragma unroll
  for (int ni = 0; ni < 4; ++ni) accO[ni] = zf;
  float m_s = -1e30f, l_s = 0.0f;   // per lane, q = lm

  auto STAGE = [&](int b, int kb) {
    int r = t >> 3, p = t & 7;
    int lc = p ^ (r & 7);
    GLD16(K  + (size_t)(kb + r) * DHEAD + lc * 8,
          (char*)&Kl[b][0] + (size_t)(w * 64) * 16);
    GLD16(Vt + (size_t)r * S_LEN + kb + lc * 8,
          (char*)&Vl[b][0] + (size_t)(w * 64) * 16);
  };

  const int NT = S_LEN / 64;
  STAGE(0, 0);
  STAGE(1, 64);

  for (int it = 0; it < NT; ++it) {
    const int cur = it & 1;
    // own tile-it loads complete (2 newest = tile it+1 may stay in flight)
    if (it < NT - 1) {
      asm volatile("s_waitcnt vmcnt(2)" ::: "memory");
    } else {
      asm volatile("s_waitcnt vmcnt(0)" ::: "memory");
    }
    __builtin_amdgcn_s_barrier();   // all waves' tile-it loads landed

    // ---- S^T = K Q^T (log2 domain): p4[ji] rows kv = ji*16+lq*4+r, col q = lm
    f32x4 p4[4];
    __builtin_amdgcn_s_setprio(1);
#pragma unroll
    for (int ji = 0; ji < 4; ++ji) {
      int rr = ji * 16 + lm;
      bf16x8 k0 = *reinterpret_cast<const bf16x8*>(
          &Kl[cur][rr * 64 + ((lq) ^ (rr & 7)) * 8]);
      bf16x8 k1 = *reinterpret_cast<const bf16x8*>(
          &Kl[cur][rr * 64 + ((4 + lq) ^ (rr & 7)) * 8]);
      f32x4 s0 = __builtin_amdgcn_mfma_f32_16x16x32_bf16(k0, aq[0], zf, 0, 0, 0);
      p4[ji]   = __builtin_amdgcn_mfma_f32_16x16x32_bf16(k1, aq[1], s0, 0, 0, 0);
    }
    __builtin_amdgcn_s_setprio(0);

    // ---- online softmax (per lane, q = lm) ----
    float t0 = fmaxf(fmaxf(p4[0][0], p4[0][1]), fmaxf(p4[0][2], p4[0][3]));
    float t1 = fmaxf(fmaxf(p4[1][0], p4[1][1]), fmaxf(p4[1][2], p4[1][3]));
    float t2 = fmaxf(fmaxf(p4[2][0], p4[2][1]), fmaxf(p4[2][2], p4[2][3]));
    float t3 = fmaxf(fmaxf(p4[3][0], p4[3][1]), fmaxf(p4[3][2], p4[3][3]));
    float tm = fmaxf(fmaxf(t0, t1), fmaxf(t2, t3));
    tm = fmaxf(tm, __shfl_xor(tm, 16));
    tm = fmaxf(tm, __shfl_xor(tm, 32));

    // defer-max: only rescale when the tile max beats running max by > THR
    if (!__all(tm - m_s <= DEFER_THR)) {
      float mn = fmaxf(m_s, tm);
      float sc = exp2f(m_s - mn);
      l_s *= sc;
      m_s = mn;
#pragma unroll
      for (int r = 0; r < 4; ++r) {
        float scr = __shfl(sc, lq * 4 + r);
#pragma unroll
        for (int ni = 0; ni < 4; ++ni) accO[ni][r] *= scr;
      }
    }

    float ps = 0.0f;
#pragma unroll
    for (int ji = 0; ji < 4; ++ji)
#pragma unroll
      for (int r = 0; r < 4; ++r) {
        float e = exp2f(p4[ji][r] - m_s);
        p4[ji][r] = e;
        ps += e;
      }
    ps += __shfl_xor(ps, 16);
    ps += __shfl_xor(ps, 32);
    l_s += ps;

    // ---- P^T -> per-wave LDS (v_cvt_pk_bf16_f32 packing) ----
    unsigned short* Pw = &Pl[w][0];
#pragma unroll
    for (int ji = 0; ji < 4; ++ji) {
      uint2 u;
      u.x = cvt_pk_bf16(p4[ji][0], p4[ji][1]);
      u.y = cvt_pk_bf16(p4[ji][2], p4[ji][3]);
      *reinterpret_cast<uint2*>(&Pw[lm * 72 + ji * 16 + lq * 4]) = u;
    }

    // ---- O += P V ----
    bf16x8 ap[2];
#pragma unroll
    for (int c = 0; c < 2; ++c)
      ap[c] = *reinterpret_cast<const bf16x8*>(&Pw[lm * 72 + c * 32 + lq * 8]);
    __builtin_amdgcn_s_setprio(1);
#pragma unroll
    for (int ni = 0; ni < 4; ++ni) {
      int dd = ni * 16 + lm;
#pragma unroll
      for (int c = 0; c < 2; ++c) {
        bf16x8 bv = *reinterpret_cast<const bf16x8*>(
            &Vl[cur][dd * 64 + ((c * 4 + lq) ^ (dd & 7)) * 8]);
        accO[ni] = __builtin_amdgcn_mfma_f32_16x16x32_bf16(ap[c], bv, accO[ni], 0, 0, 0);
      }
    }
    __builtin_amdgcn_s_setprio(0);

    // all of this wave's LDS reads of buf[cur] retired before reuse barrier
    asm volatile("s_waitcnt lgkmcnt(0)" ::: "memory");
    __builtin_amdgcn_sched_barrier(0);
    __builtin_amdgcn_s_barrier();

    if (it + 2 < NT) STAGE(cur, (it + 2) * 64);
  }

  // ---- epilogue: normalize, write ctx [S,B,E] bf16 ----
  const int b = bh >> 4, h = bh & 15;
#pragma unroll
  for (int r = 0; r < 4; ++r) {
    float rl = 1.0f / __shfl(l_s, lq * 4 + r);
    int srow = qw + lq * 4 + r;
    size_t rowbase = ((size_t)srow * BATCH + b) * EMB + (size_t)h * 64;
#pragma unroll
    for (int ni = 0; ni < 4; ++ni)
      Ctx[rowbase + ni * 16 + lm] = f2b(accO[ni][r] * rl);
  }
}

// ---------------- launch ----------------
extern "C" void kernel_launch(void* const* d_in, const int* in_sizes, int n_in,
                              void* d_out, int out_size, void* d_ws, size_t ws_size,
                              hipStream_t stream) {
  const float* query = (const float*)d_in[0];
  const float* wq = (const float*)d_in[1];
  const float* bq = (const float*)d_in[2];
  const float* wk = (const float*)d_in[3];
  const float* bk = (const float*)d_in[4];
  const float* wv = (const float*)d_in[5];
  const float* bv = (const float*)d_in[6];
  const float* wo = (const float*)d_in[7];
  const float* bo = (const float*)d_in[8];
  float* out = (float*)d_out;

  unsigned short* p = (unsigned short*)d_ws;
  unsigned short* Xbf = p;                        p += (size_t)ROWS * EMB;
  unsigned short* Wqb = p;                        p += (size_t)EMB * EMB;
  unsigned short* Wkb = p;                        p += (size_t)EMB * EMB;
  unsigned short* Wvb = p;                        p += (size_t)EMB * EMB;
  unsigned short* Wob = p;                        p += (size_t)EMB * EMB;
  unsigned short* Qb  = p;                        p += (size_t)ROWS * EMB;   // [B,H,S,DH]
  unsigned short* Kb  = p;                        p += (size_t)ROWS * EMB;
  unsigned short* Vb  = p;                        p += (size_t)ROWS * EMB;
  unsigned short* Ctx = p;                        p += (size_t)ROWS * EMB;
  unsigned short* Vtg = Xbf;   // reuse Xbf after gemm_qkv consumed it

  cvt_kernel<<<ROWS * EMB / 8 / 256, 256, 0, stream>>>(query, Xbf);
  cvt4_kernel<<<dim3(EMB * EMB / 8 / 256, 4), 256, 0, stream>>>(
      wq, wk, wv, wo, Wqb, Wkb, Wvb, Wob);
  gemm_qkv_kernel<<<dim3(ROWS / 128, EMB / 128, 3), 256, 0, stream>>>(
      Xbf, Wqb, Wkb, Wvb, bq, bk, bv, Qb, Kb, Vb);
  transpose_v_kernel<<<dim3(BATCH * NH, S_LEN / 64), 256, 0, stream>>>(Vb, Vtg);
  attn_kernel<<<dim3(BATCH * NH, S_LEN / 128), 512, 0, stream>>>(Qb, Kb, Vtg, Ctx);
  gemm_out_kernel<<<dim3(ROWS / 128, EMB / 128), 256, 0, stream>>>(Ctx, Wob, bo, out);
}

// Round 6
// 206.686 us; speedup vs baseline: 1.6393x; 1.0758x over previous
//
#include <hip/hip_runtime.h>
#include <hip/hip_bf16.h>
#include <stdint.h>

// Problem constants
#define S_LEN 2048
#define BATCH 2
#define EMB   1024
#define NH    16
#define DHEAD 64
#define ROWS  (S_LEN*BATCH)   // 4096
// DH^-0.5 * log2(e): scores produced in log2 domain so softmax uses raw v_exp_f32
#define SCALE_Q 0.18033688011112042f
#define DEFER_THR 11.0f       // log2-domain defer-max threshold (P <= 2^11)

typedef __attribute__((ext_vector_type(8))) short bf16x8;   // 8 bf16 in 4 VGPRs
typedef __attribute__((ext_vector_type(4))) float f32x4;

typedef const __attribute__((address_space(1))) void* gas_ptr;
typedef __attribute__((address_space(3))) void* las_ptr;
// async global->LDS, 16B per lane, dest = wave-uniform base + lane*16
#define GLD16(g, l) __builtin_amdgcn_global_load_lds((gas_ptr)(g), (las_ptr)(l), 16, 0, 0)

__device__ __forceinline__ unsigned short f2b(float f) {
  union { float f; unsigned int u; } v; v.f = f;
  unsigned int u = v.u;
  unsigned int r = (u + 0x7FFFu + ((u >> 16) & 1u)) >> 16;  // RNE
  return (unsigned short)r;
}

__device__ __forceinline__ unsigned cvt_pk_bf16(float lo, float hi) {
  unsigned r;
  asm("v_cvt_pk_bf16_f32 %0, %1, %2" : "=v"(r) : "v"(lo), "v"(hi));
  return r;
}

// raw 2^x — single transcendental instruction, no ocml edge-case bloat
__device__ __forceinline__ float exp2_raw(float x) {
  float r;
  asm("v_exp_f32 %0, %1" : "=v"(r) : "v"(x));
  return r;
}

// ---------------- fused fp32 -> bf16 conversion (query + 4 weights) ----------------
__device__ __forceinline__ void cvt8(const float* __restrict__ s,
                                     unsigned short* __restrict__ d, size_t i) {
  float4 a = *reinterpret_cast<const float4*>(s + i);
  float4 b = *reinterpret_cast<const float4*>(s + i + 4);
  uint4 o;
  o.x = (unsigned)f2b(a.x) | ((unsigned)f2b(a.y) << 16);
  o.y = (unsigned)f2b(a.z) | ((unsigned)f2b(a.w) << 16);
  o.z = (unsigned)f2b(b.x) | ((unsigned)f2b(b.y) << 16);
  o.w = (unsigned)f2b(b.z) | ((unsigned)f2b(b.w) << 16);
  *reinterpret_cast<uint4*>(d + i) = o;
}

__global__ __launch_bounds__(256) void cvt_all_kernel(
    const float* __restrict__ query,
    const float* __restrict__ wq, const float* __restrict__ wk,
    const float* __restrict__ wv, const float* __restrict__ wo,
    unsigned short* __restrict__ Xbf,
    unsigned short* __restrict__ Wqb, unsigned short* __restrict__ Wkb,
    unsigned short* __restrict__ Wvb, unsigned short* __restrict__ Wob) {
  int id = blockIdx.x;
  const float* s; unsigned short* d; size_t off;
  if (id < 2048) { s = query; d = Xbf; off = (size_t)id * 2048; }
  else {
    int wsel = (id - 2048) >> 9;
    off = (size_t)((id - 2048) & 511) * 2048;
    switch (wsel) {
      case 0:  s = wq; d = Wqb; break;
      case 1:  s = wk; d = Wkb; break;
      case 2:  s = wv; d = Wvb; break;
      default: s = wo; d = Wob; break;
    }
  }
  cvt8(s, d, off + (size_t)threadIdx.x * 8);
}

// ---------------- GEMM mainloop (C = A * B^T), 128x128 tile, BK=64 ----------------
// m97 structure: SINGLE-buffered 32 KB LDS, per K-step:
// stage -> vmcnt0+barrier -> ds_read+MFMA -> barrier. XOR swizzle both-sides.
__device__ __forceinline__ void gemm_mainloop(const unsigned short* __restrict__ A,
                                              const unsigned short* __restrict__ Bw,
                                              int m0, int n0, f32x4 acc[4][4],
                                              unsigned short* Ab, unsigned short* Bb) {
  const int t    = threadIdx.x;
  const int lane = t & 63;
  const int w    = t >> 6;
  const int wr   = w >> 1, wc = w & 1;
  const int lm   = lane & 15;
  const int lq   = lane >> 4;

  f32x4 zf = {0.0f, 0.0f, 0.0f, 0.0f};
#pragma unroll
  for (int i = 0; i < 4; ++i)
#pragma unroll
    for (int j = 0; j < 4; ++j) acc[i][j] = zf;

  for (int k0 = 0; k0 < EMB; k0 += 64) {
    // stage 128x64 A-tile + B-tile: chunk c -> row c>>3, phys slot c&7 holds
    // logical column-chunk (c&7)^(row&7) (inverse swizzle on source address).
#pragma unroll
    for (int q = 0; q < 4; ++q) {
      int c = t + q * 256;
      int r = c >> 3, ci = c & 7;
      int lc = ci ^ (r & 7);
      GLD16(A  + (size_t)(m0 + r) * EMB + k0 + lc * 8,
            (char*)Ab + (size_t)(q * 256 + w * 64) * 16);
      GLD16(Bw + (size_t)(n0 + r) * EMB + k0 + lc * 8,
            (char*)Bb + (size_t)(q * 256 + w * 64) * 16);
    }
    asm volatile("s_waitcnt vmcnt(0)" ::: "memory");
    __syncthreads();

#pragma unroll
    for (int kk = 0; kk < 2; ++kk) {
      bf16x8 af[4], bfr[4];
#pragma unroll
      for (int i = 0; i < 4; ++i) {
        int ra = wr * 64 + i * 16 + lm;
        af[i] = *reinterpret_cast<const bf16x8*>(
            &Ab[ra * 64 + ((kk * 4 + lq) ^ (ra & 7)) * 8]);
      }
#pragma unroll
      for (int j = 0; j < 4; ++j) {
        int rb = wc * 64 + j * 16 + lm;
        bfr[j] = *reinterpret_cast<const bf16x8*>(
            &Bb[rb * 64 + ((kk * 4 + lq) ^ (rb & 7)) * 8]);
      }
#pragma unroll
      for (int i = 0; i < 4; ++i)
#pragma unroll
        for (int j = 0; j < 4; ++j)
          acc[i][j] = __builtin_amdgcn_mfma_f32_16x16x32_bf16(af[i], bfr[j], acc[i][j], 0, 0, 0);
    }
    __syncthreads();
  }
}

// ---------------- QKV projection (V written pre-transposed) ----------------
__global__ __launch_bounds__(256) void gemm_qkv_kernel(
    const unsigned short* __restrict__ X,
    const unsigned short* __restrict__ Wq, const unsigned short* __restrict__ Wk,
    const unsigned short* __restrict__ Wv,
    const float* __restrict__ bq, const float* __restrict__ bk, const float* __restrict__ bv,
    unsigned short* __restrict__ Qb, unsigned short* __restrict__ Kb,
    unsigned short* __restrict__ Vtg) {
  __shared__ unsigned short SH[2][128 * 64];
  const int m0 = blockIdx.x * 128;
  const int n0 = blockIdx.y * 128;
  const int z  = blockIdx.z;
  const unsigned short* Bw = (z == 0) ? Wq : (z == 1) ? Wk : Wv;
  const float* bias        = (z == 0) ? bq : (z == 1) ? bk : bv;

  f32x4 acc[4][4];
  gemm_mainloop(X, Bw, m0, n0, acc, SH[0], SH[1]);

  const int t    = threadIdx.x;
  const int lane = t & 63;
  const int w    = t >> 6;
  const int wr   = w >> 1, wc = w & 1;
  const int lm   = lane & 15, lq = lane >> 4;

  if (z != 2) {
    // Q/K: scatter to [B,H,S,DH] bf16 (Q scaled into log2 domain)
    unsigned short* Out = (z == 0) ? Qb : Kb;
    const float scale   = (z == 0) ? SCALE_Q : 1.0f;
#pragma unroll
    for (int j = 0; j < 4; ++j) {
      int col = n0 + wc * 64 + j * 16 + lm;      // E index
      int h = col >> 6, dd = col & 63;
      float bc = bias[col];
#pragma unroll
      for (int i = 0; i < 4; ++i) {
#pragma unroll
        for (int r = 0; r < 4; ++r) {
          int row = m0 + wr * 64 + i * 16 + lq * 4 + r;   // s*B + b
          int s = row >> 1, b = row & 1;
          float v = (acc[i][j][r] + bc) * scale;
          Out[((size_t)(b * NH + h) * S_LEN + s) * DHEAD + dd] = f2b(v);
        }
      }
    }
  } else {
    // V: transpose in LDS, write Vt[bh][d][s] coalesced.
    // T logical [col 128][idx 128], idx = (row&1)*64 + (row>>1) = b*64 + s'.
    // 16B-chunk XOR swizzle: phys chunk = (b*8 + c3) ^ (col&7) on low 3 bits.
    unsigned short* T = &SH[0][0];   // 128*128 shorts = 32 KB
#pragma unroll
    for (int j = 0; j < 4; ++j) {
      int col = wc * 64 + j * 16 + lm;           // local col 0..127
      float bc = bias[n0 + col];
#pragma unroll
      for (int i = 0; i < 4; ++i) {
#pragma unroll
        for (int r = 0; r < 4; ++r) {
          int row = wr * 64 + i * 16 + lq * 4 + r;   // local row 0..127
          int idx = (row & 1) * 64 + (row >> 1);
          int chunk = idx >> 3, within = idx & 7;
          int pchunk = (chunk & 8) | ((chunk ^ col) & 7);
          T[col * 128 + pchunk * 8 + within] = f2b(acc[i][j][r] + bc);
        }
      }
    }
    __syncthreads();
    // write-out: 8 iters x 256 threads; unit u = col+128*b, 8 lanes x 16B each
#pragma unroll
    for (int itr = 0; itr < 8; ++itr) {
      int u = (t >> 3) + itr * 32;
      int col = u & 127, b = u >> 7;
      int c3 = t & 7;
      int pchunk = (b * 8) | ((c3 ^ col) & 7);
      bf16x8 vv = *reinterpret_cast<const bf16x8*>(&T[col * 128 + pchunk * 8]);
      int h = (n0 + col) >> 6, dd = (n0 + col) & 63;
      *reinterpret_cast<bf16x8*>(
          Vtg + ((size_t)(b * NH + h) * DHEAD + dd) * S_LEN + (m0 >> 1) + c3 * 8) = vv;
    }
  }
}

// ---------------- final projection ----------------
__global__ __launch_bounds__(256) void gemm_out_kernel(
    const unsigned short* __restrict__ Ctx, const unsigned short* __restrict__ Wo,
    const float* __restrict__ bo, float* __restrict__ Out) {
  __shared__ unsigned short SH[2][128 * 64];
  const int m0 = blockIdx.x * 128;
  const int n0 = blockIdx.y * 128;
  f32x4 acc[4][4];
  gemm_mainloop(Ctx, Wo, m0, n0, acc, SH[0], SH[1]);

  const int lane = threadIdx.x & 63;
  const int w    = threadIdx.x >> 6;
  const int wr   = w >> 1, wc = w & 1;
  const int lm   = lane & 15, lq = lane >> 4;
#pragma unroll
  for (int j = 0; j < 4; ++j) {
    int col = n0 + wc * 64 + j * 16 + lm;
    float bc = bo[col];
#pragma unroll
    for (int i = 0; i < 4; ++i) {
#pragma unroll
      for (int r = 0; r < 4; ++r) {
        int row = m0 + wr * 64 + i * 16 + lq * 4 + r;
        Out[(size_t)row * EMB + col] = acc[i][j][r] + bc;
      }
    }
  }
}

// ---------------- flash attention, swapped-QK^T, log2-domain softmax ----------------
// 2-deep counted-vmcnt pipeline, raw s_barrier, no mid-loop vmcnt(0) drain.
__global__ __launch_bounds__(512) void attn_kernel(
    const unsigned short* __restrict__ Qb, const unsigned short* __restrict__ Kb,
    const unsigned short* __restrict__ Vtg, unsigned short* __restrict__ Ctx) {
  const int bh = blockIdx.x;
  const int q0 = blockIdx.y * 128;
  const int t    = threadIdx.x;
  const int lane = t & 63;
  const int w    = t >> 6;
  const int lm   = lane & 15, lq = lane >> 4;
  const unsigned short* Q  = Qb  + (size_t)bh * S_LEN * DHEAD;
  const unsigned short* K  = Kb  + (size_t)bh * S_LEN * DHEAD;
  const unsigned short* Vt = Vtg + (size_t)bh * DHEAD * S_LEN;   // [d][s]

  __shared__ unsigned short Kl[2][64 * 64];   // [kv][d], swizzled
  __shared__ unsigned short Vl[2][64 * 64];   // [d][kv], swizzled
  __shared__ unsigned short Pl[8][16 * 72];   // per-wave P[q][kv], stride 72

  const int qw = q0 + w * 16;

  bf16x8 aq[2];
#pragma unroll
  for (int c = 0; c < 2; ++c)
    aq[c] = *reinterpret_cast<const bf16x8*>(
        Q + (size_t)(qw + lm) * DHEAD + c * 32 + lq * 8);

  // loop-invariant swizzled LDS byte offsets
  int koff[2][4], voff[4][2];
#pragma unroll
  for (int ji = 0; ji < 4; ++ji) {
    int rr = ji * 16 + lm;
    koff[0][ji] = (rr * 64 + ((lq) ^ (rr & 7)) * 8) * 2;
    koff[1][ji] = (rr * 64 + ((4 + lq) ^ (rr & 7)) * 8) * 2;
  }
#pragma unroll
  for (int ni = 0; ni < 4; ++ni) {
    int dd = ni * 16 + lm;
    voff[ni][0] = (dd * 64 + ((lq) ^ (dd & 7)) * 8) * 2;
    voff[ni][1] = (dd * 64 + ((4 + lq) ^ (dd & 7)) * 8) * 2;
  }

  f32x4 zf = {0.0f, 0.0f, 0.0f, 0.0f};
  f32x4 accO[4];                // O[q=lq*4+r][d=ni*16+lm]
#pragma unroll
  for (int ni = 0; ni < 4; ++ni) accO[ni] = zf;
  float m_s = -1e30f, l_s = 0.0f;   // per lane, q = lm

  auto STAGE = [&](int b, int kb) {
    int r = t >> 3, p = t & 7;
    int lc = p ^ (r & 7);
    GLD16(K  + (size_t)(kb + r) * DHEAD + lc * 8,
          (char*)&Kl[b][0] + (size_t)(w * 64) * 16);
    GLD16(Vt + (size_t)r * S_LEN + kb + lc * 8,
          (char*)&Vl[b][0] + (size_t)(w * 64) * 16);
  };

  const int NT = S_LEN / 64;
  STAGE(0, 0);
  STAGE(1, 64);

  for (int it = 0; it < NT; ++it) {
    const int cur = it & 1;
    if (it < NT - 1) {
      asm volatile("s_waitcnt vmcnt(2)" ::: "memory");
    } else {
      asm volatile("s_waitcnt vmcnt(0)" ::: "memory");
    }
    __builtin_amdgcn_s_barrier();   // all waves' tile-it loads landed

    // ---- S^T = K Q^T (log2 domain): p4[ji] rows kv = ji*16+lq*4+r, col q = lm
    const char* Kb8 = (const char*)&Kl[cur][0];
    f32x4 p4[4];
    __builtin_amdgcn_s_setprio(1);
#pragma unroll
    for (int ji = 0; ji < 4; ++ji) {
      bf16x8 k0 = *reinterpret_cast<const bf16x8*>(Kb8 + koff[0][ji]);
      bf16x8 k1 = *reinterpret_cast<const bf16x8*>(Kb8 + koff[1][ji]);
      f32x4 s0 = __builtin_amdgcn_mfma_f32_16x16x32_bf16(k0, aq[0], zf, 0, 0, 0);
      p4[ji]   = __builtin_amdgcn_mfma_f32_16x16x32_bf16(k1, aq[1], s0, 0, 0, 0);
    }
    __builtin_amdgcn_s_setprio(0);

    // ---- online softmax (per lane, q = lm) ----
    float t0 = fmaxf(fmaxf(p4[0][0], p4[0][1]), fmaxf(p4[0][2], p4[0][3]));
    float t1 = fmaxf(fmaxf(p4[1][0], p4[1][1]), fmaxf(p4[1][2], p4[1][3]));
    float t2 = fmaxf(fmaxf(p4[2][0], p4[2][1]), fmaxf(p4[2][2], p4[2][3]));
    float t3 = fmaxf(fmaxf(p4[3][0], p4[3][1]), fmaxf(p4[3][2], p4[3][3]));
    float tm = fmaxf(fmaxf(t0, t1), fmaxf(t2, t3));
    tm = fmaxf(tm, __shfl_xor(tm, 16));
    tm = fmaxf(tm, __shfl_xor(tm, 32));

    // defer-max: only rescale when the tile max beats running max by > THR
    if (!__all(tm - m_s <= DEFER_THR)) {
      float mn = fmaxf(m_s, tm);
      float sc = exp2_raw(m_s - mn);
      l_s *= sc;
      m_s = mn;
#pragma unroll
      for (int r = 0; r < 4; ++r) {
        float scr = __shfl(sc, lq * 4 + r);
#pragma unroll
        for (int ni = 0; ni < 4; ++ni) accO[ni][r] *= scr;
      }
    }

    float ps = 0.0f;
#pragma unroll
    for (int ji = 0; ji < 4; ++ji)
#pragma unroll
      for (int r = 0; r < 4; ++r) {
        float e = exp2_raw(p4[ji][r] - m_s);
        p4[ji][r] = e;
        ps += e;
      }
    ps += __shfl_xor(ps, 16);
    ps += __shfl_xor(ps, 32);
    l_s += ps;

    // ---- P^T -> per-wave LDS (v_cvt_pk_bf16_f32 packing) ----
    unsigned short* Pw = &Pl[w][0];
#pragma unroll
    for (int ji = 0; ji < 4; ++ji) {
      uint2 u;
      u.x = cvt_pk_bf16(p4[ji][0], p4[ji][1]);
      u.y = cvt_pk_bf16(p4[ji][2], p4[ji][3]);
      *reinterpret_cast<uint2*>(&Pw[lm * 72 + ji * 16 + lq * 4]) = u;
    }

    // ---- O += P V ----
    bf16x8 ap[2];
#pragma unroll
    for (int c = 0; c < 2; ++c)
      ap[c] = *reinterpret_cast<const bf16x8*>(&Pw[lm * 72 + c * 32 + lq * 8]);
    const char* Vb8 = (const char*)&Vl[cur][0];
    __builtin_amdgcn_s_setprio(1);
#pragma unroll
    for (int ni = 0; ni < 4; ++ni) {
#pragma unroll
      for (int c = 0; c < 2; ++c) {
        bf16x8 bv = *reinterpret_cast<const bf16x8*>(Vb8 + voff[ni][c]);
        accO[ni] = __builtin_amdgcn_mfma_f32_16x16x32_bf16(ap[c], bv, accO[ni], 0, 0, 0);
      }
    }
    __builtin_amdgcn_s_setprio(0);

    // all of this wave's LDS reads of buf[cur] retired before reuse barrier
    asm volatile("s_waitcnt lgkmcnt(0)" ::: "memory");
    __builtin_amdgcn_sched_barrier(0);
    __builtin_amdgcn_s_barrier();

    if (it + 2 < NT) STAGE(cur, (it + 2) * 64);
  }

  // ---- epilogue: normalize, write ctx [S,B,E] bf16 ----
  const int b = bh >> 4, h = bh & 15;
#pragma unroll
  for (int r = 0; r < 4; ++r) {
    float rl = 1.0f / __shfl(l_s, lq * 4 + r);
    int srow = qw + lq * 4 + r;
    size_t rowbase = ((size_t)srow * BATCH + b) * EMB + (size_t)h * 64;
#pragma unroll
    for (int ni = 0; ni < 4; ++ni)
      Ctx[rowbase + ni * 16 + lm] = f2b(accO[ni][r] * rl);
  }
}

// ---------------- launch ----------------
extern "C" void kernel_launch(void* const* d_in, const int* in_sizes, int n_in,
                              void* d_out, int out_size, void* d_ws, size_t ws_size,
                              hipStream_t stream) {
  const float* query = (const float*)d_in[0];
  const float* wq = (const float*)d_in[1];
  const float* bq = (const float*)d_in[2];
  const float* wk = (const float*)d_in[3];
  const float* bk = (const float*)d_in[4];
  const float* wv = (const float*)d_in[5];
  const float* bv = (const float*)d_in[6];
  const float* wo = (const float*)d_in[7];
  const float* bo = (const float*)d_in[8];
  float* out = (float*)d_out;

  unsigned short* p = (unsigned short*)d_ws;
  unsigned short* Xbf = p;                        p += (size_t)ROWS * EMB;
  unsigned short* Wqb = p;                        p += (size_t)EMB * EMB;
  unsigned short* Wkb = p;                        p += (size_t)EMB * EMB;
  unsigned short* Wvb = p;                        p += (size_t)EMB * EMB;
  unsigned short* Wob = p;                        p += (size_t)EMB * EMB;
  unsigned short* Qb  = p;                        p += (size_t)ROWS * EMB;   // [B,H,S,DH]
  unsigned short* Kb  = p;                        p += (size_t)ROWS * EMB;   // [B,H,S,DH]
  unsigned short* Vtg = p;                        p += (size_t)ROWS * EMB;   // [B,H,DH,S]
  unsigned short* Ctx = p;                        p += (size_t)ROWS * EMB;

  cvt_all_kernel<<<4096, 256, 0, stream>>>(query, wq, wk, wv, wo,
                                           Xbf, Wqb, Wkb, Wvb, Wob);
  gemm_qkv_kernel<<<dim3(ROWS / 128, EMB / 128, 3), 256, 0, stream>>>(
      Xbf, Wqb, Wkb, Wvb, bq, bk, bv, Qb, Kb, Vtg);
  attn_kernel<<<dim3(BATCH * NH, S_LEN / 128), 512, 0, stream>>>(Qb, Kb, Vtg, Ctx);
  gemm_out_kernel<<<dim3(ROWS / 128, EMB / 128), 256, 0, stream>>>(Ctx, Wob, bo, out);
}

// Round 7
// 196.014 us; speedup vs baseline: 1.7286x; 1.0544x over previous
//
#include <hip/hip_runtime.h>
#include <hip/hip_bf16.h>
#include <stdint.h>

// Problem constants
#define S_LEN 2048
#define BATCH 2
#define EMB   1024
#define NH    16
#define DHEAD 64
#define ROWS  (S_LEN*BATCH)   // 4096
// DH^-0.5 * log2(e): scores produced in log2 domain so softmax uses raw v_exp_f32
#define SCALE_Q 0.18033688011112042f
#define DEFER_THR 11.0f       // log2-domain defer-max threshold (P <= 2^11)

typedef __attribute__((ext_vector_type(8))) short bf16x8;    // 8 bf16 in 4 VGPRs
typedef __attribute__((ext_vector_type(4))) float f32x4;
typedef __attribute__((ext_vector_type(16))) float f32x16;

typedef const __attribute__((address_space(1))) void* gas_ptr;
typedef __attribute__((address_space(3))) void* las_ptr;
// async global->LDS, 16B per lane, dest = wave-uniform base + lane*16
#define GLD16(g, l) __builtin_amdgcn_global_load_lds((gas_ptr)(g), (las_ptr)(l), 16, 0, 0)

__device__ __forceinline__ unsigned short f2b(float f) {
  union { float f; unsigned int u; } v; v.f = f;
  unsigned int u = v.u;
  unsigned int r = (u + 0x7FFFu + ((u >> 16) & 1u)) >> 16;  // RNE
  return (unsigned short)r;
}

__device__ __forceinline__ unsigned cvt_pk_bf16(float lo, float hi) {
  unsigned r;
  asm("v_cvt_pk_bf16_f32 %0, %1, %2" : "=v"(r) : "v"(lo), "v"(hi));
  return r;
}

// raw 2^x — single transcendental instruction, no ocml edge-case bloat
__device__ __forceinline__ float exp2_raw(float x) {
  float r;
  asm("v_exp_f32 %0, %1" : "=v"(r) : "v"(x));
  return r;
}

// ---------------- fused fp32 -> bf16 conversion (query + 4 weights) ----------------
__device__ __forceinline__ void cvt8(const float* __restrict__ s,
                                     unsigned short* __restrict__ d, size_t i) {
  float4 a = *reinterpret_cast<const float4*>(s + i);
  float4 b = *reinterpret_cast<const float4*>(s + i + 4);
  uint4 o;
  o.x = (unsigned)f2b(a.x) | ((unsigned)f2b(a.y) << 16);
  o.y = (unsigned)f2b(a.z) | ((unsigned)f2b(a.w) << 16);
  o.z = (unsigned)f2b(b.x) | ((unsigned)f2b(b.y) << 16);
  o.w = (unsigned)f2b(b.z) | ((unsigned)f2b(b.w) << 16);
  *reinterpret_cast<uint4*>(d + i) = o;
}

__global__ __launch_bounds__(256) void cvt_all_kernel(
    const float* __restrict__ query,
    const float* __restrict__ wq, const float* __restrict__ wk,
    const float* __restrict__ wv, const float* __restrict__ wo,
    unsigned short* __restrict__ Xbf,
    unsigned short* __restrict__ Wqb, unsigned short* __restrict__ Wkb,
    unsigned short* __restrict__ Wvb, unsigned short* __restrict__ Wob) {
  int id = blockIdx.x;
  const float* s; unsigned short* d; size_t off;
  if (id < 2048) { s = query; d = Xbf; off = (size_t)id * 2048; }
  else {
    int wsel = (id - 2048) >> 9;
    off = (size_t)((id - 2048) & 511) * 2048;
    switch (wsel) {
      case 0:  s = wq; d = Wqb; break;
      case 1:  s = wk; d = Wkb; break;
      case 2:  s = wv; d = Wvb; break;
      default: s = wo; d = Wob; break;
    }
  }
  cvt8(s, d, off + (size_t)threadIdx.x * 8);
}

// ---------------- GEMM mainloop (C = A * B^T), 128x128 tile, BK=64 ----------------
__device__ __forceinline__ void gemm_mainloop(const unsigned short* __restrict__ A,
                                              const unsigned short* __restrict__ Bw,
                                              int m0, int n0, f32x4 acc[4][4],
                                              unsigned short* Ab, unsigned short* Bb) {
  const int t    = threadIdx.x;
  const int lane = t & 63;
  const int w    = t >> 6;
  const int wr   = w >> 1, wc = w & 1;
  const int lm   = lane & 15;
  const int lq   = lane >> 4;

  f32x4 zf = {0.0f, 0.0f, 0.0f, 0.0f};
#pragma unroll
  for (int i = 0; i < 4; ++i)
#pragma unroll
    for (int j = 0; j < 4; ++j) acc[i][j] = zf;

  for (int k0 = 0; k0 < EMB; k0 += 64) {
#pragma unroll
    for (int q = 0; q < 4; ++q) {
      int c = t + q * 256;
      int r = c >> 3, ci = c & 7;
      int lc = ci ^ (r & 7);
      GLD16(A  + (size_t)(m0 + r) * EMB + k0 + lc * 8,
            (char*)Ab + (size_t)(q * 256 + w * 64) * 16);
      GLD16(Bw + (size_t)(n0 + r) * EMB + k0 + lc * 8,
            (char*)Bb + (size_t)(q * 256 + w * 64) * 16);
    }
    asm volatile("s_waitcnt vmcnt(0)" ::: "memory");
    __syncthreads();

#pragma unroll
    for (int kk = 0; kk < 2; ++kk) {
      bf16x8 af[4], bfr[4];
#pragma unroll
      for (int i = 0; i < 4; ++i) {
        int ra = wr * 64 + i * 16 + lm;
        af[i] = *reinterpret_cast<const bf16x8*>(
            &Ab[ra * 64 + ((kk * 4 + lq) ^ (ra & 7)) * 8]);
      }
#pragma unroll
      for (int j = 0; j < 4; ++j) {
        int rb = wc * 64 + j * 16 + lm;
        bfr[j] = *reinterpret_cast<const bf16x8*>(
            &Bb[rb * 64 + ((kk * 4 + lq) ^ (rb & 7)) * 8]);
      }
#pragma unroll
      for (int i = 0; i < 4; ++i)
#pragma unroll
        for (int j = 0; j < 4; ++j)
          acc[i][j] = __builtin_amdgcn_mfma_f32_16x16x32_bf16(af[i], bfr[j], acc[i][j], 0, 0, 0);
    }
    __syncthreads();
  }
}

// ---------------- QKV projection (V written pre-transposed + kv-permuted) ----------------
__global__ __launch_bounds__(256) void gemm_qkv_kernel(
    const unsigned short* __restrict__ X,
    const unsigned short* __restrict__ Wq, const unsigned short* __restrict__ Wk,
    const unsigned short* __restrict__ Wv,
    const float* __restrict__ bq, const float* __restrict__ bk, const float* __restrict__ bv,
    unsigned short* __restrict__ Qb, unsigned short* __restrict__ Kb,
    unsigned short* __restrict__ Vtg) {
  __shared__ unsigned short SH[2][128 * 64];
  const int m0 = blockIdx.x * 128;
  const int n0 = blockIdx.y * 128;
  const int z  = blockIdx.z;
  const unsigned short* Bw = (z == 0) ? Wq : (z == 1) ? Wk : Wv;
  const float* bias        = (z == 0) ? bq : (z == 1) ? bk : bv;

  f32x4 acc[4][4];
  gemm_mainloop(X, Bw, m0, n0, acc, SH[0], SH[1]);

  const int t    = threadIdx.x;
  const int lane = t & 63;
  const int w    = t >> 6;
  const int wr   = w >> 1, wc = w & 1;
  const int lm   = lane & 15, lq = lane >> 4;

  if (z != 2) {
    unsigned short* Out = (z == 0) ? Qb : Kb;
    const float scale   = (z == 0) ? SCALE_Q : 1.0f;
#pragma unroll
    for (int j = 0; j < 4; ++j) {
      int col = n0 + wc * 64 + j * 16 + lm;      // E index
      int h = col >> 6, dd = col & 63;
      float bc = bias[col];
#pragma unroll
      for (int i = 0; i < 4; ++i) {
#pragma unroll
        for (int r = 0; r < 4; ++r) {
          int row = m0 + wr * 64 + i * 16 + lq * 4 + r;   // s*B + b
          int s = row >> 1, b = row & 1;
          float v = (acc[i][j][r] + bc) * scale;
          Out[((size_t)(b * NH + h) * S_LEN + s) * DHEAD + dd] = f2b(v);
        }
      }
    }
  } else {
    // V: transpose in LDS, write Vt[bh][d][s'] with kv bits2<->3 swapped per
    // 16-group (matches attn's in-register P ordering for the PV MFMA).
    unsigned short* T = &SH[0][0];   // 128*128 shorts = 32 KB
#pragma unroll
    for (int j = 0; j < 4; ++j) {
      int col = wc * 64 + j * 16 + lm;           // local col 0..127
      float bc = bias[n0 + col];
#pragma unroll
      for (int i = 0; i < 4; ++i) {
#pragma unroll
        for (int r = 0; r < 4; ++r) {
          int row = wr * 64 + i * 16 + lq * 4 + r;   // local row 0..127
          int idx = (row & 1) * 64 + (row >> 1);
          int chunk = idx >> 3, within = idx & 7;
          int pchunk = (chunk & 8) | ((chunk ^ col) & 7);
          T[col * 128 + pchunk * 8 + within] = f2b(acc[i][j][r] + bc);
        }
      }
    }
    __syncthreads();
#pragma unroll
    for (int itr = 0; itr < 8; ++itr) {
      int u = (t >> 3) + itr * 32;
      int col = u & 127, b = u >> 7;
      int c3 = t & 7;
      int pchunk = (b * 8) | ((c3 ^ col) & 7);
      bf16x8 vv = *reinterpret_cast<const bf16x8*>(&T[col * 128 + pchunk * 8]);
      int h = (n0 + col) >> 6, dd = (n0 + col) & 63;
      unsigned short* dst =
          Vtg + ((size_t)(b * NH + h) * DHEAD + dd) * S_LEN + (m0 >> 1);
      // kv-permute store: 8-run c3*8 -> two 4-runs (swap bits 2,3)
      int p1 = ((c3 >> 1) << 4) | ((c3 & 1) << 2);
      union { bf16x8 v; uint4 u4; } cv; cv.v = vv;
      *reinterpret_cast<uint2*>(dst + p1)     = make_uint2(cv.u4.x, cv.u4.y);
      *reinterpret_cast<uint2*>(dst + p1 + 8) = make_uint2(cv.u4.z, cv.u4.w);
    }
  }
}

// ---------------- final projection: 64x128 tile (512 blocks = 2/CU) ----------------
__global__ __launch_bounds__(256) void gemm_out_kernel(
    const unsigned short* __restrict__ Ctx, const unsigned short* __restrict__ Wo,
    const float* __restrict__ bo, float* __restrict__ Out) {
  __shared__ unsigned short Ab[64 * 64];    // 8 KB
  __shared__ unsigned short Bb[128 * 64];   // 16 KB
  const int m0 = blockIdx.x * 64;
  const int n0 = blockIdx.y * 128;
  const int t    = threadIdx.x;
  const int lane = t & 63;
  const int w    = t >> 6;
  const int wr   = w >> 1, wc = w & 1;
  const int lm   = lane & 15, lq = lane >> 4;

  f32x4 zf = {0.0f, 0.0f, 0.0f, 0.0f};
  f32x4 acc[2][4];
#pragma unroll
  for (int i = 0; i < 2; ++i)
#pragma unroll
    for (int j = 0; j < 4; ++j) acc[i][j] = zf;

  for (int k0 = 0; k0 < EMB; k0 += 64) {
#pragma unroll
    for (int q = 0; q < 2; ++q) {
      int c = t + q * 256;
      int r = c >> 3, ci = c & 7;
      int lc = ci ^ (r & 7);
      GLD16(Ctx + (size_t)(m0 + r) * EMB + k0 + lc * 8,
            (char*)Ab + (size_t)(q * 256 + w * 64) * 16);
    }
#pragma unroll
    for (int q = 0; q < 4; ++q) {
      int c = t + q * 256;
      int r = c >> 3, ci = c & 7;
      int lc = ci ^ (r & 7);
      GLD16(Wo + (size_t)(n0 + r) * EMB + k0 + lc * 8,
            (char*)Bb + (size_t)(q * 256 + w * 64) * 16);
    }
    asm volatile("s_waitcnt vmcnt(0)" ::: "memory");
    __syncthreads();

#pragma unroll
    for (int kk = 0; kk < 2; ++kk) {
      bf16x8 af[2], bfr[4];
#pragma unroll
      for (int i = 0; i < 2; ++i) {
        int ra = wr * 32 + i * 16 + lm;
        af[i] = *reinterpret_cast<const bf16x8*>(
            &Ab[ra * 64 + ((kk * 4 + lq) ^ (ra & 7)) * 8]);
      }
#pragma unroll
      for (int j = 0; j < 4; ++j) {
        int rb = wc * 64 + j * 16 + lm;
        bfr[j] = *reinterpret_cast<const bf16x8*>(
            &Bb[rb * 64 + ((kk * 4 + lq) ^ (rb & 7)) * 8]);
      }
#pragma unroll
      for (int i = 0; i < 2; ++i)
#pragma unroll
        for (int j = 0; j < 4; ++j)
          acc[i][j] = __builtin_amdgcn_mfma_f32_16x16x32_bf16(af[i], bfr[j], acc[i][j], 0, 0, 0);
    }
    __syncthreads();
  }

#pragma unroll
  for (int j = 0; j < 4; ++j) {
    int col = n0 + wc * 64 + j * 16 + lm;
    float bc = bo[col];
#pragma unroll
    for (int i = 0; i < 2; ++i) {
#pragma unroll
      for (int r = 0; r < 4; ++r) {
        int row = m0 + wr * 32 + i * 16 + lq * 4 + r;
        Out[(size_t)row * EMB + col] = acc[i][j][r] + bc;
      }
    }
  }
}

// ---------------- flash attention: 32x32x16 MFMA, 32 q/wave, in-register P ----------------
// 4 waves x 32 q = 128 q/block, grid (32,16)=512 blocks (2/CU). KVBLK=64,
// K/V double-buffered, counted-vmcnt pipeline. Swapped QK^T: C col=lane&31=q
// matches PV A-operand row=lane&31=q -> P stays in registers (cvt_pk only);
// V global layout is kv-permuted so B-fragments align with P's natural order.
__global__ __launch_bounds__(256, 2) void attn_kernel(
    const unsigned short* __restrict__ Qb, const unsigned short* __restrict__ Kb,
    const unsigned short* __restrict__ Vtg, unsigned short* __restrict__ Ctx) {
  const int bh = blockIdx.x;
  const int q0 = blockIdx.y * 128;
  const int t    = threadIdx.x;
  const int lane = t & 63;
  const int w    = t >> 6;
  const int l31  = lane & 31;
  const int hh   = lane >> 5;
  const unsigned short* Q  = Qb  + (size_t)bh * S_LEN * DHEAD;
  const unsigned short* K  = Kb  + (size_t)bh * S_LEN * DHEAD;
  const unsigned short* Vt = Vtg + (size_t)bh * DHEAD * S_LEN;   // [d][s-permuted]

  __shared__ unsigned short Kl[2][64 * 64];   // [kv][d], swizzled
  __shared__ unsigned short Vl[2][64 * 64];   // [d][kv-slot], swizzled

  const int qw = q0 + w * 32;

  // Q B-frags: lane holds col q = l31, k = kk*16 + hh*8 + e
  bf16x8 aq[4];
#pragma unroll
  for (int kk = 0; kk < 4; ++kk)
    aq[kk] = *reinterpret_cast<const bf16x8*>(
        Q + (size_t)(qw + l31) * DHEAD + kk * 16 + hh * 8);

  f32x16 z16 = {0.f,0.f,0.f,0.f, 0.f,0.f,0.f,0.f, 0.f,0.f,0.f,0.f, 0.f,0.f,0.f,0.f};
  f32x16 accO[2];               // O[q-rows][d = ni*32 + l31]
  accO[0] = z16; accO[1] = z16;
  float m_s = -1e30f, l_s = 0.0f;   // per lane, q = l31

  auto STAGE = [&](int b, int kb) {
#pragma unroll
    for (int q = 0; q < 2; ++q) {
      int c = t + q * 256;
      int r = c >> 3, p = c & 7;
      int lc = p ^ (r & 7);
      GLD16(K  + (size_t)(kb + r) * DHEAD + lc * 8,
            (char*)&Kl[b][0] + (size_t)(q * 256 + w * 64) * 16);
      GLD16(Vt + (size_t)r * S_LEN + kb + lc * 8,
            (char*)&Vl[b][0] + (size_t)(q * 256 + w * 64) * 16);
    }
  };

  const int NT = S_LEN / 64;
  STAGE(0, 0);
  STAGE(1, 64);

  for (int it = 0; it < NT; ++it) {
    const int cur = it & 1;
    if (it < NT - 1) {
      asm volatile("s_waitcnt vmcnt(4)" ::: "memory");
    } else {
      asm volatile("s_waitcnt vmcnt(0)" ::: "memory");
    }
    __builtin_amdgcn_s_barrier();   // tile-it loads landed for all waves

    // ---- S^T = K Q^T (log2 domain): p32[ji] C-frag, col q = l31 ----
    f32x16 p32[2];
    __builtin_amdgcn_s_setprio(1);
#pragma unroll
    for (int ji = 0; ji < 2; ++ji) {
      f32x16 a = z16;
      int rr = ji * 32 + l31;
#pragma unroll
      for (int kk = 0; kk < 4; ++kk) {
        bf16x8 kf = *reinterpret_cast<const bf16x8*>(
            &Kl[cur][rr * 64 + ((kk * 2 + hh) ^ (rr & 7)) * 8]);
        a = __builtin_amdgcn_mfma_f32_32x32x16_bf16(kf, aq[kk], a, 0, 0, 0);
      }
      p32[ji] = a;
    }
    __builtin_amdgcn_s_setprio(0);

    // ---- online softmax (per lane, q = l31), tree reduce + 1 cross-half op ----
    float t8[8];
#pragma unroll
    for (int e = 0; e < 8; ++e)
      t8[e] = fmaxf(fmaxf(p32[0][e], p32[0][e + 8]),
                    fmaxf(p32[1][e], p32[1][e + 8]));
    float u0 = fmaxf(t8[0], t8[4]), u1 = fmaxf(t8[1], t8[5]);
    float u2 = fmaxf(t8[2], t8[6]), u3 = fmaxf(t8[3], t8[7]);
    float tm = fmaxf(fmaxf(u0, u1), fmaxf(u2, u3));
    tm = fmaxf(tm, __shfl_xor(tm, 32));

    if (!__all(tm - m_s <= DEFER_THR)) {
      float mn = fmaxf(m_s, tm);
      float sc = exp2_raw(m_s - mn);
      l_s *= sc;
      m_s = mn;
#pragma unroll
      for (int r = 0; r < 16; ++r) {
        float scr = __shfl(sc, (r & 3) + 8 * (r >> 2) + 4 * hh);
        accO[0][r] *= scr;
        accO[1][r] *= scr;
      }
    }

#pragma unroll
    for (int e = 0; e < 16; ++e) {
      p32[0][e] = exp2_raw(p32[0][e] - m_s);
      p32[1][e] = exp2_raw(p32[1][e] - m_s);
    }
    float s8[8];
#pragma unroll
    for (int e = 0; e < 8; ++e)
      s8[e] = (p32[0][e] + p32[0][e + 8]) + (p32[1][e] + p32[1][e + 8]);
    float v0 = (s8[0] + s8[4]) + (s8[1] + s8[5]);
    float v1 = (s8[2] + s8[6]) + (s8[3] + s8[7]);
    float ps = v0 + v1;
    ps += __shfl_xor(ps, 32);
    l_s += ps;

    // ---- P -> bf16 A-frags entirely in-register (kv-order matches V layout) ----
    bf16x8 pa[2][2];
#pragma unroll
    for (int ji = 0; ji < 2; ++ji) {
      uint4 lo4, hi4;
      lo4.x = cvt_pk_bf16(p32[ji][0],  p32[ji][1]);
      lo4.y = cvt_pk_bf16(p32[ji][2],  p32[ji][3]);
      lo4.z = cvt_pk_bf16(p32[ji][4],  p32[ji][5]);
      lo4.w = cvt_pk_bf16(p32[ji][6],  p32[ji][7]);
      hi4.x = cvt_pk_bf16(p32[ji][8],  p32[ji][9]);
      hi4.y = cvt_pk_bf16(p32[ji][10], p32[ji][11]);
      hi4.z = cvt_pk_bf16(p32[ji][12], p32[ji][13]);
      hi4.w = cvt_pk_bf16(p32[ji][14], p32[ji][15]);
      pa[ji][0] = *reinterpret_cast<bf16x8*>(&lo4);
      pa[ji][1] = *reinterpret_cast<bf16x8*>(&hi4);
    }

    // ---- O += P V ----
    __builtin_amdgcn_s_setprio(1);
#pragma unroll
    for (int ni = 0; ni < 2; ++ni) {
      int dd = ni * 32 + l31;
#pragma unroll
      for (int ji = 0; ji < 2; ++ji)
#pragma unroll
        for (int ss = 0; ss < 2; ++ss) {
          bf16x8 bv = *reinterpret_cast<const bf16x8*>(
              &Vl[cur][dd * 64 + ((ji * 4 + ss * 2 + hh) ^ (dd & 7)) * 8]);
          accO[ni] = __builtin_amdgcn_mfma_f32_32x32x16_bf16(pa[ji][ss], bv, accO[ni], 0, 0, 0);
        }
    }
    __builtin_amdgcn_s_setprio(0);

    // all LDS reads of buf[cur] retired before reuse barrier
    asm volatile("s_waitcnt lgkmcnt(0)" ::: "memory");
    __builtin_amdgcn_sched_barrier(0);
    __builtin_amdgcn_s_barrier();

    if (it + 2 < NT) STAGE(cur, (it + 2) * 64);
  }

  // ---- epilogue: normalize, write ctx [S,B,E] bf16 ----
  const int b = bh >> 4, h = bh & 15;
#pragma unroll
  for (int r = 0; r < 16; ++r) {
    int row = (r & 3) + 8 * (r >> 2) + 4 * hh;
    float rl = 1.0f / __shfl(l_s, row);
    int srow = qw + row;
    size_t base = ((size_t)srow * BATCH + b) * EMB + (size_t)h * 64 + l31;
    Ctx[base]      = f2b(accO[0][r] * rl);
    Ctx[base + 32] = f2b(accO[1][r] * rl);
  }
}

// ---------------- launch ----------------
extern "C" void kernel_launch(void* const* d_in, const int* in_sizes, int n_in,
                              void* d_out, int out_size, void* d_ws, size_t ws_size,
                              hipStream_t stream) {
  const float* query = (const float*)d_in[0];
  const float* wq = (const float*)d_in[1];
  const float* bq = (const float*)d_in[2];
  const float* wk = (const float*)d_in[3];
  const float* bk = (const float*)d_in[4];
  const float* wv = (const float*)d_in[5];
  const float* bv = (const float*)d_in[6];
  const float* wo = (const float*)d_in[7];
  const float* bo = (const float*)d_in[8];
  float* out = (float*)d_out;

  unsigned short* p = (unsigned short*)d_ws;
  unsigned short* Xbf = p;                        p += (size_t)ROWS * EMB;
  unsigned short* Wqb = p;                        p += (size_t)EMB * EMB;
  unsigned short* Wkb = p;                        p += (size_t)EMB * EMB;
  unsigned short* Wvb = p;                        p += (size_t)EMB * EMB;
  unsigned short* Wob = p;                        p += (size_t)EMB * EMB;
  unsigned short* Qb  = p;                        p += (size_t)ROWS * EMB;   // [B,H,S,DH]
  unsigned short* Kb  = p;                        p += (size_t)ROWS * EMB;   // [B,H,S,DH]
  unsigned short* Vtg = p;                        p += (size_t)ROWS * EMB;   // [B,H,DH,S] kv-permuted
  unsigned short* Ctx = p;                        p += (size_t)ROWS * EMB;

  cvt_all_kernel<<<4096, 256, 0, stream>>>(query, wq, wk, wv, wo,
                                           Xbf, Wqb, Wkb, Wvb, Wob);
  gemm_qkv_kernel<<<dim3(ROWS / 128, EMB / 128, 3), 256, 0, stream>>>(
      Xbf, Wqb, Wkb, Wvb, bq, bk, bv, Qb, Kb, Vtg);
  attn_kernel<<<dim3(BATCH * NH, S_LEN / 128), 256, 0, stream>>>(Qb, Kb, Vtg, Ctx);
  gemm_out_kernel<<<dim3(ROWS / 64, EMB / 128), 256, 0, stream>>>(Ctx, Wob, bo, out);
}